// Round 1
// baseline (3255.331 us; speedup 1.0000x reference)
//
#include <hip/hip_runtime.h>
#include <hip/hip_bf16.h>

// Problem constants (from reference setup_inputs)
#define NN 100000
#define HH 128
#define RR 30
#define NE 600000
#define TILE 64
#define EPAD (NE + RR * TILE)
#define BN_EPS 1e-5f

typedef __bf16 v8bf __attribute__((ext_vector_type(8)));
typedef float  v4f  __attribute__((ext_vector_type(4)));

static __device__ __forceinline__ unsigned short f2b(float f) {
    unsigned int u = __float_as_uint(f);
    unsigned int r = (u + 0x7FFF + ((u >> 16) & 1)) >> 16;  // RNE
    return (unsigned short)r;
}

// ---------------- histogram: per-(dst,rel) degree + per-rel count ----------------
__global__ void k_hist(const int* __restrict__ dst, const int* __restrict__ et,
                       int* __restrict__ deg, int* __restrict__ cnt) {
    int i = blockIdx.x * blockDim.x + threadIdx.x;
    if (i >= NE) return;
    int d = dst[i], r = et[i];
    atomicAdd(&deg[d * RR + r], 1);
    atomicAdd(&cnt[r], 1);
}

// ---------------- scan: chunk offsets, pad fill, cursor init ----------------
__global__ void k_scan(const int* __restrict__ cnt, int* __restrict__ cursor,
                       int* __restrict__ totals,
                       int* __restrict__ src_s, int* __restrict__ dst_s,
                       int* __restrict__ et_s, float* __restrict__ norm_s) {
    __shared__ int off[RR + 1];
    if (threadIdx.x == 0) {
        int acc = 0;
        for (int r = 0; r < RR; ++r) {
            off[r] = acc;
            acc += (cnt[r] + TILE - 1) / TILE;
        }
        off[RR] = acc;
        totals[0] = acc * TILE;
    }
    __syncthreads();
    for (int r = 0; r < RR; ++r) {
        int begin = off[r] * TILE + cnt[r];
        int end   = off[r + 1] * TILE;
        for (int p = begin + (int)threadIdx.x; p < end; p += blockDim.x) {
            src_s[p] = 0; dst_s[p] = 0; et_s[p] = r; norm_s[p] = 0.f;
        }
    }
    if (threadIdx.x == 0)
        for (int r = 0; r < RR; ++r) cursor[r] = off[r] * TILE;
}

// ---------------- scatter into relation-sorted arrays ----------------
__global__ void k_scatter(const int* __restrict__ src, const int* __restrict__ dst,
                          const int* __restrict__ et, const int* __restrict__ deg,
                          int* __restrict__ cursor,
                          int* __restrict__ src_s, int* __restrict__ dst_s,
                          int* __restrict__ et_s, float* __restrict__ norm_s) {
    int i = blockIdx.x * blockDim.x + threadIdx.x;
    if (i >= NE) return;
    int r = et[i], d = dst[i];
    int pos = atomicAdd(&cursor[r], 1);
    src_s[pos] = src[i];
    dst_s[pos] = d;
    et_s[pos]  = r;
    int dg = deg[d * RR + r];
    norm_s[pos] = 1.0f / (float)(dg > 1 ? dg : 1);
}

// ---------------- convert+transpose weights to bf16: Wt[m][c][k] = W[m][k][c] ----
__global__ void k_convW(const float* __restrict__ W, unsigned short* __restrict__ Wt,
                        int total) {
    int idx = blockIdx.x * blockDim.x + threadIdx.x;
    if (idx >= total) return;
    int m = idx / (HH * HH);
    int rem = idx % (HH * HH);
    int k = rem / HH, c = rem % HH;
    Wt[m * HH * HH + c * HH + k] = f2b(W[idx]);
}

// ---------------- embedding lookup -> bf16 h ----------------
__global__ void k_embed(const int* __restrict__ x, const float* __restrict__ emb,
                        unsigned short* __restrict__ hb) {
    int idx = blockIdx.x * blockDim.x + threadIdx.x;
    if (idx >= NN * HH) return;
    int i = idx / HH, j = idx % HH;
    hb[idx] = f2b(emb[x[i] * HH + j]);
}

// ---------------- root GEMM: tmp = h @ root + bias ----------------
__global__ __launch_bounds__(256) void k_rootgemm(const unsigned short* __restrict__ hb,
                                                  const unsigned short* __restrict__ rootT,
                                                  const float* __restrict__ bias,
                                                  float* __restrict__ tmp) {
    __shared__ __align__(16) unsigned short Xs[TILE][HH + 8];
    __shared__ __align__(16) unsigned short Ws[HH][HH + 8];
    int base = blockIdx.x * TILE;
    int t = threadIdx.x;

    // stage X: 64 rows x 128 bf16; 4 threads/row, uint4 (8 bf16) x4 iters
    {
        int l = t >> 2, lr = t & 3;
        int row = base + l;
        for (int i = 0; i < 4; ++i) {
            int g = lr + 4 * i;
            uint4 v = {0u, 0u, 0u, 0u};
            if (row < NN) v = *reinterpret_cast<const uint4*>(hb + (size_t)row * HH + g * 8);
            *reinterpret_cast<uint4*>(&Xs[l][g * 8]) = v;
        }
    }
    // stage W^T (128x128 bf16)
    for (int i = 0; i < 8; ++i) {
        int idx = t + 256 * i;
        int row = idx >> 4, g = idx & 15;
        *reinterpret_cast<uint4*>(&Ws[row][g * 8]) =
            *reinterpret_cast<const uint4*>(rootT + row * HH + g * 8);
    }
    __syncthreads();

    int w = t >> 6, lane = t & 63;
    int lr16 = lane & 15, kg = lane >> 4;
    v4f acc[8];
    for (int n = 0; n < 8; ++n) acc[n] = (v4f){0.f, 0.f, 0.f, 0.f};
#pragma unroll
    for (int kk = 0; kk < 4; ++kk) {
        int k0 = kk * 32 + kg * 8;
        v8bf a = *reinterpret_cast<const v8bf*>(&Xs[w * 16 + lr16][k0]);
#pragma unroll
        for (int n = 0; n < 8; ++n) {
            v8bf b = *reinterpret_cast<const v8bf*>(&Ws[n * 16 + lr16][k0]);
            acc[n] = __builtin_amdgcn_mfma_f32_16x16x32_bf16(a, b, acc[n], 0, 0, 0);
        }
    }
#pragma unroll
    for (int n = 0; n < 8; ++n)
        for (int j = 0; j < 4; ++j) {
            int row = base + w * 16 + kg * 4 + j;
            int col = n * 16 + lr16;
            if (row < NN) tmp[(size_t)row * HH + col] = acc[n][j] + bias[col];
        }
}

// ---------------- edge GEMM: tmp[dst] += (h[src] @ W[r]) * norm ----------------
__global__ __launch_bounds__(256) void k_edgegemm(const unsigned short* __restrict__ hb,
                                                  const unsigned short* __restrict__ Wt,
                                                  const int* __restrict__ src_s,
                                                  const int* __restrict__ dst_s,
                                                  const int* __restrict__ et_s,
                                                  const float* __restrict__ norm_s,
                                                  const int* __restrict__ totals,
                                                  float* __restrict__ tmp) {
    int ebase = blockIdx.x * TILE;
    if (ebase >= totals[0]) return;
    __shared__ __align__(16) unsigned short Xs[TILE][HH + 8];
    __shared__ __align__(16) unsigned short Ws[HH][HH + 8];
    __shared__ int   src_l[TILE];
    __shared__ int   dst_l[TILE];
    __shared__ float nrm_l[TILE];
    int t = threadIdx.x;
    if (t < TILE) {
        src_l[t] = src_s[ebase + t];
        dst_l[t] = dst_s[ebase + t];
        nrm_l[t] = norm_s[ebase + t];
    }
    int rel = et_s[ebase];  // chunk is single-relation by construction
    __syncthreads();

    {
        int l = t >> 2, lr = t & 3;
        int srow = src_l[l];
        for (int i = 0; i < 4; ++i) {
            int g = lr + 4 * i;
            *reinterpret_cast<uint4*>(&Xs[l][g * 8]) =
                *reinterpret_cast<const uint4*>(hb + (size_t)srow * HH + g * 8);
        }
    }
    const unsigned short* Wr = Wt + (size_t)rel * HH * HH;
    for (int i = 0; i < 8; ++i) {
        int idx = t + 256 * i;
        int row = idx >> 4, g = idx & 15;
        *reinterpret_cast<uint4*>(&Ws[row][g * 8]) =
            *reinterpret_cast<const uint4*>(Wr + row * HH + g * 8);
    }
    __syncthreads();

    int w = t >> 6, lane = t & 63;
    int lr16 = lane & 15, kg = lane >> 4;
    v4f acc[8];
    for (int n = 0; n < 8; ++n) acc[n] = (v4f){0.f, 0.f, 0.f, 0.f};
#pragma unroll
    for (int kk = 0; kk < 4; ++kk) {
        int k0 = kk * 32 + kg * 8;
        v8bf a = *reinterpret_cast<const v8bf*>(&Xs[w * 16 + lr16][k0]);
#pragma unroll
        for (int n = 0; n < 8; ++n) {
            v8bf b = *reinterpret_cast<const v8bf*>(&Ws[n * 16 + lr16][k0]);
            acc[n] = __builtin_amdgcn_mfma_f32_16x16x32_bf16(a, b, acc[n], 0, 0, 0);
        }
    }
#pragma unroll
    for (int n = 0; n < 8; ++n)
        for (int j = 0; j < 4; ++j) {
            int slot = w * 16 + kg * 4 + j;
            int col  = n * 16 + lr16;
            float v  = acc[n][j] * nrm_l[slot];
            atomicAdd(&tmp[(size_t)dst_l[slot] * HH + col], v);
        }
}

// ---------------- BN: column sums ----------------
__global__ void k_bnsum(const float* __restrict__ tmp, float* __restrict__ sums,
                        float* __restrict__ sumsq) {
    int col = threadIdx.x & 127;
    int half = threadIdx.x >> 7;
    int base = blockIdx.x * 512;
    float s = 0.f, s2 = 0.f;
    for (int r = half; r < 512; r += 2) {
        int row = base + r;
        if (row < NN) {
            float v = tmp[(size_t)row * HH + col];
            s += v; s2 += v * v;
        }
    }
    __shared__ float sh[2][128], sh2[2][128];
    sh[half][col] = s; sh2[half][col] = s2;
    __syncthreads();
    if (half == 0) {
        atomicAdd(&sums[col], s + sh[1][col]);
        atomicAdd(&sumsq[col], s2 + sh2[1][col]);
    }
}

// ---------------- BN apply + ReLU ----------------
__global__ void k_bnapply(const float* __restrict__ tmp, const float* __restrict__ sums,
                          const float* __restrict__ sumsq, const float* __restrict__ g,
                          const float* __restrict__ be, unsigned short* __restrict__ hout,
                          float* __restrict__ fout, int write_bf16) {
    int idx = blockIdx.x * blockDim.x + threadIdx.x;
    if (idx >= NN * HH) return;
    int col = idx & 127;
    float inv_n = 1.0f / (float)NN;
    float mean = sums[col] * inv_n;
    float var = sumsq[col] * inv_n - mean * mean;
    float sc = g[col] * rsqrtf(var + BN_EPS);
    float v = (tmp[idx] - mean) * sc + be[col];
    v = fmaxf(v, 0.f);
    if (write_bf16) hout[idx] = f2b(v);
    else fout[idx] = v;
}

// ---------------- workspace layout ----------------
constexpr size_t OFF_DEG  = 0;                                    // N*R*4 = 12,000,000
constexpr size_t OFF_HB   = OFF_DEG + (size_t)NN * RR * 4;        // N*H*2
constexpr size_t OFF_TMP  = OFF_HB + (size_t)NN * HH * 2;         // N*H*4
constexpr size_t OFF_W1T  = OFF_TMP + (size_t)NN * HH * 4;
constexpr size_t OFF_W2T  = OFF_W1T + (size_t)RR * HH * HH * 2;
constexpr size_t OFF_R1T  = OFF_W2T + (size_t)RR * HH * HH * 2;
constexpr size_t OFF_R2T  = OFF_R1T + (size_t)HH * HH * 2;
constexpr size_t OFF_SRCS = OFF_R2T + (size_t)HH * HH * 2;
constexpr size_t OFF_DSTS = OFF_SRCS + (size_t)EPAD * 4;
constexpr size_t OFF_ETS  = OFF_DSTS + (size_t)EPAD * 4;
constexpr size_t OFF_NRMS = OFF_ETS + (size_t)EPAD * 4;
constexpr size_t OFF_CTRL = OFF_NRMS + (size_t)EPAD * 4;          // cnt[32],cursor[32],totals
constexpr size_t OFF_BNS  = OFF_CTRL + 512;
constexpr size_t OFF_BNSQ = OFF_BNS + 512;
constexpr size_t WS_NEED  = OFF_BNSQ + 512;                       // ~100.5 MB

extern "C" void kernel_launch(void* const* d_in, const int* in_sizes, int n_in,
                              void* d_out, int out_size, void* d_ws, size_t ws_size,
                              hipStream_t stream) {
    const int*   x     = (const int*)d_in[0];
    const int*   eidx  = (const int*)d_in[1];   // (2,E) row-major: src then dst
    const int*   et    = (const int*)d_in[2];
    const float* emb   = (const float*)d_in[3];
    const float* W1    = (const float*)d_in[4];
    const float* root1 = (const float*)d_in[5];
    const float* b1    = (const float*)d_in[6];
    const float* g1    = (const float*)d_in[7];
    const float* be1   = (const float*)d_in[8];
    const float* W2    = (const float*)d_in[9];
    const float* root2 = (const float*)d_in[10];
    const float* b2    = (const float*)d_in[11];
    const float* g2    = (const float*)d_in[12];
    const float* be2   = (const float*)d_in[13];
    float* out = (float*)d_out;

    if (ws_size < WS_NEED) return;  // diagnosable: out stays poisoned

    char* ws = (char*)d_ws;
    int*   deg    = (int*)(ws + OFF_DEG);
    unsigned short* hb = (unsigned short*)(ws + OFF_HB);
    float* tmp    = (float*)(ws + OFF_TMP);
    unsigned short* W1t = (unsigned short*)(ws + OFF_W1T);
    unsigned short* W2t = (unsigned short*)(ws + OFF_W2T);
    unsigned short* r1t = (unsigned short*)(ws + OFF_R1T);
    unsigned short* r2t = (unsigned short*)(ws + OFF_R2T);
    int*   src_s  = (int*)(ws + OFF_SRCS);
    int*   dst_s  = (int*)(ws + OFF_DSTS);
    int*   et_s   = (int*)(ws + OFF_ETS);
    float* norm_s = (float*)(ws + OFF_NRMS);
    int*   cnt    = (int*)(ws + OFF_CTRL);
    int*   cursor = cnt + 32;
    int*   totals = cnt + 64;
    float* bnsum  = (float*)(ws + OFF_BNS);
    float* bnsq   = (float*)(ws + OFF_BNSQ);

    const int* srcp = eidx;
    const int* dstp = eidx + NE;

    hipMemsetAsync(deg, 0, (size_t)NN * RR * 4, stream);
    hipMemsetAsync(cnt, 0, 512, stream);

    k_hist<<<(NE + 255) / 256, 256, 0, stream>>>(dstp, et, deg, cnt);
    k_scan<<<1, 256, 0, stream>>>(cnt, cursor, totals, src_s, dst_s, et_s, norm_s);
    k_scatter<<<(NE + 255) / 256, 256, 0, stream>>>(srcp, dstp, et, deg, cursor,
                                                    src_s, dst_s, et_s, norm_s);
    k_convW<<<(RR * HH * HH + 255) / 256, 256, 0, stream>>>(W1, W1t, RR * HH * HH);
    k_convW<<<(RR * HH * HH + 255) / 256, 256, 0, stream>>>(W2, W2t, RR * HH * HH);
    k_convW<<<(HH * HH + 255) / 256, 256, 0, stream>>>(root1, r1t, HH * HH);
    k_convW<<<(HH * HH + 255) / 256, 256, 0, stream>>>(root2, r2t, HH * HH);
    k_embed<<<(NN * HH + 255) / 256, 256, 0, stream>>>(x, emb, hb);

    const unsigned short* Wts[2]   = {W1t, W2t};
    const unsigned short* rts[2]   = {r1t, r2t};
    const float* biases[2] = {b1, b2};
    const float* gs[2]     = {g1, g2};
    const float* bes[2]    = {be1, be2};

    for (int layer = 0; layer < 2; ++layer) {
        hipMemsetAsync(bnsum, 0, 512, stream);
        hipMemsetAsync(bnsq, 0, 512, stream);
        k_rootgemm<<<(NN + TILE - 1) / TILE, 256, 0, stream>>>(hb, rts[layer],
                                                               biases[layer], tmp);
        k_edgegemm<<<EPAD / TILE, 256, 0, stream>>>(hb, Wts[layer], src_s, dst_s,
                                                    et_s, norm_s, totals, tmp);
        k_bnsum<<<(NN + 511) / 512, 256, 0, stream>>>(tmp, bnsum, bnsq);
        k_bnapply<<<(NN * HH + 255) / 256, 256, 0, stream>>>(tmp, bnsum, bnsq,
                                                             gs[layer], bes[layer],
                                                             hb, out, layer == 0);
    }
}

// Round 2
// 1048.510 us; speedup vs baseline: 3.1047x; 3.1047x over previous
//
#include <hip/hip_runtime.h>
#include <hip/hip_bf16.h>

// Problem constants (from reference setup_inputs)
#define NN 100000
#define HH 128
#define RR 30
#define NE 600000
#define TILE 64
#define EPAD (NE + RR * TILE)
#define BN_EPS 1e-5f

typedef __bf16 v8bf __attribute__((ext_vector_type(8)));
typedef float  v4f  __attribute__((ext_vector_type(4)));

static __device__ __forceinline__ unsigned short f2b(float f) {
    unsigned int u = __float_as_uint(f);
    unsigned int r = (u + 0x7FFF + ((u >> 16) & 1)) >> 16;  // RNE
    return (unsigned short)r;
}

// ---------------- histogram: per-(dst,rel) degree + per-rel count ----------------
// Per-block LDS histogram for the 30-bin relation count: avoids 600k global
// atomics onto 30 addresses (same-address serialization was 1.14 ms).
__global__ void k_hist(const int* __restrict__ dst, const int* __restrict__ et,
                       int* __restrict__ deg, int* __restrict__ cnt) {
    __shared__ int lh[RR];
    int t = threadIdx.x;
    if (t < RR) lh[t] = 0;
    __syncthreads();
    int i = blockIdx.x * blockDim.x + t;
    if (i < NE) {
        int d = dst[i], r = et[i];
        atomicAdd(&deg[d * RR + r], 1);   // scattered: runs at memory speed
        atomicAdd(&lh[r], 1);             // LDS: cheap
    }
    __syncthreads();
    if (t < RR && lh[t]) atomicAdd(&cnt[t], lh[t]);  // 30 atomics/block max
}

// ---------------- scan: chunk offsets, pad fill, cursor init ----------------
__global__ void k_scan(const int* __restrict__ cnt, int* __restrict__ cursor,
                       int* __restrict__ totals,
                       int* __restrict__ src_s, int* __restrict__ dst_s,
                       int* __restrict__ et_s, float* __restrict__ norm_s) {
    __shared__ int off[RR + 1];
    if (threadIdx.x == 0) {
        int acc = 0;
        for (int r = 0; r < RR; ++r) {
            off[r] = acc;
            acc += (cnt[r] + TILE - 1) / TILE;
        }
        off[RR] = acc;
        totals[0] = acc * TILE;
    }
    __syncthreads();
    for (int r = 0; r < RR; ++r) {
        int begin = off[r] * TILE + cnt[r];
        int end   = off[r + 1] * TILE;
        for (int p = begin + (int)threadIdx.x; p < end; p += blockDim.x) {
            src_s[p] = 0; dst_s[p] = 0; et_s[p] = r; norm_s[p] = 0.f;
        }
    }
    if (threadIdx.x == 0)
        for (int r = 0; r < RR; ++r) cursor[r] = off[r] * TILE;
}

// ---------------- scatter into relation-sorted arrays ----------------
// Per-block chunk reservation: LDS histogram -> one cursor atomic per
// (block, rel) -> thread position = block base + local rank.
__global__ void k_scatter(const int* __restrict__ src, const int* __restrict__ dst,
                          const int* __restrict__ et, const int* __restrict__ deg,
                          int* __restrict__ cursor,
                          int* __restrict__ src_s, int* __restrict__ dst_s,
                          int* __restrict__ et_s, float* __restrict__ norm_s) {
    __shared__ int lh[RR];
    __shared__ int lbase[RR];
    int t = threadIdx.x;
    if (t < RR) lh[t] = 0;
    __syncthreads();
    int i = blockIdx.x * blockDim.x + t;
    int r = 0, d = 0, lrank = 0;
    bool valid = (i < NE);
    if (valid) {
        r = et[i]; d = dst[i];
        lrank = atomicAdd(&lh[r], 1);
    }
    __syncthreads();
    if (t < RR && lh[t]) lbase[t] = atomicAdd(&cursor[t], lh[t]);
    __syncthreads();
    if (valid) {
        int pos = lbase[r] + lrank;
        src_s[pos] = src[i];
        dst_s[pos] = d;
        et_s[pos]  = r;
        int dg = deg[d * RR + r];
        norm_s[pos] = 1.0f / (float)(dg > 1 ? dg : 1);
    }
}

// ---------------- convert+transpose weights to bf16: Wt[m][c][k] = W[m][k][c] ----
__global__ void k_convW(const float* __restrict__ W, unsigned short* __restrict__ Wt,
                        int total) {
    int idx = blockIdx.x * blockDim.x + threadIdx.x;
    if (idx >= total) return;
    int m = idx / (HH * HH);
    int rem = idx % (HH * HH);
    int k = rem / HH, c = rem % HH;
    Wt[m * HH * HH + c * HH + k] = f2b(W[idx]);
}

// ---------------- embedding lookup -> bf16 h ----------------
__global__ void k_embed(const int* __restrict__ x, const float* __restrict__ emb,
                        unsigned short* __restrict__ hb) {
    int idx = blockIdx.x * blockDim.x + threadIdx.x;
    if (idx >= NN * HH) return;
    int i = idx / HH, j = idx % HH;
    hb[idx] = f2b(emb[x[i] * HH + j]);
}

// ---------------- root GEMM: tmp = h @ root + bias ----------------
__global__ __launch_bounds__(256) void k_rootgemm(const unsigned short* __restrict__ hb,
                                                  const unsigned short* __restrict__ rootT,
                                                  const float* __restrict__ bias,
                                                  float* __restrict__ tmp) {
    __shared__ __align__(16) unsigned short Xs[TILE][HH + 8];
    __shared__ __align__(16) unsigned short Ws[HH][HH + 8];
    int base = blockIdx.x * TILE;
    int t = threadIdx.x;

    // stage X: 64 rows x 128 bf16; 4 threads/row, uint4 (8 bf16) x4 iters
    {
        int l = t >> 2, lr = t & 3;
        int row = base + l;
        for (int i = 0; i < 4; ++i) {
            int g = lr + 4 * i;
            uint4 v = {0u, 0u, 0u, 0u};
            if (row < NN) v = *reinterpret_cast<const uint4*>(hb + (size_t)row * HH + g * 8);
            *reinterpret_cast<uint4*>(&Xs[l][g * 8]) = v;
        }
    }
    // stage W^T (128x128 bf16)
    for (int i = 0; i < 8; ++i) {
        int idx = t + 256 * i;
        int row = idx >> 4, g = idx & 15;
        *reinterpret_cast<uint4*>(&Ws[row][g * 8]) =
            *reinterpret_cast<const uint4*>(rootT + row * HH + g * 8);
    }
    __syncthreads();

    int w = t >> 6, lane = t & 63;
    int lr16 = lane & 15, kg = lane >> 4;
    v4f acc[8];
    for (int n = 0; n < 8; ++n) acc[n] = (v4f){0.f, 0.f, 0.f, 0.f};
#pragma unroll
    for (int kk = 0; kk < 4; ++kk) {
        int k0 = kk * 32 + kg * 8;
        v8bf a = *reinterpret_cast<const v8bf*>(&Xs[w * 16 + lr16][k0]);
#pragma unroll
        for (int n = 0; n < 8; ++n) {
            v8bf b = *reinterpret_cast<const v8bf*>(&Ws[n * 16 + lr16][k0]);
            acc[n] = __builtin_amdgcn_mfma_f32_16x16x32_bf16(a, b, acc[n], 0, 0, 0);
        }
    }
#pragma unroll
    for (int n = 0; n < 8; ++n)
        for (int j = 0; j < 4; ++j) {
            int row = base + w * 16 + kg * 4 + j;
            int col = n * 16 + lr16;
            if (row < NN) tmp[(size_t)row * HH + col] = acc[n][j] + bias[col];
        }
}

// ---------------- edge GEMM: tmp[dst] += (h[src] @ W[r]) * norm ----------------
__global__ __launch_bounds__(256) void k_edgegemm(const unsigned short* __restrict__ hb,
                                                  const unsigned short* __restrict__ Wt,
                                                  const int* __restrict__ src_s,
                                                  const int* __restrict__ dst_s,
                                                  const int* __restrict__ et_s,
                                                  const float* __restrict__ norm_s,
                                                  const int* __restrict__ totals,
                                                  float* __restrict__ tmp) {
    int ebase = blockIdx.x * TILE;
    if (ebase >= totals[0]) return;
    __shared__ __align__(16) unsigned short Xs[TILE][HH + 8];
    __shared__ __align__(16) unsigned short Ws[HH][HH + 8];
    __shared__ int   src_l[TILE];
    __shared__ int   dst_l[TILE];
    __shared__ float nrm_l[TILE];
    int t = threadIdx.x;
    if (t < TILE) {
        src_l[t] = src_s[ebase + t];
        dst_l[t] = dst_s[ebase + t];
        nrm_l[t] = norm_s[ebase + t];
    }
    int rel = et_s[ebase];  // chunk is single-relation by construction
    __syncthreads();

    {
        int l = t >> 2, lr = t & 3;
        int srow = src_l[l];
        for (int i = 0; i < 4; ++i) {
            int g = lr + 4 * i;
            *reinterpret_cast<uint4*>(&Xs[l][g * 8]) =
                *reinterpret_cast<const uint4*>(hb + (size_t)srow * HH + g * 8);
        }
    }
    const unsigned short* Wr = Wt + (size_t)rel * HH * HH;
    for (int i = 0; i < 8; ++i) {
        int idx = t + 256 * i;
        int row = idx >> 4, g = idx & 15;
        *reinterpret_cast<uint4*>(&Ws[row][g * 8]) =
            *reinterpret_cast<const uint4*>(Wr + row * HH + g * 8);
    }
    __syncthreads();

    int w = t >> 6, lane = t & 63;
    int lr16 = lane & 15, kg = lane >> 4;
    v4f acc[8];
    for (int n = 0; n < 8; ++n) acc[n] = (v4f){0.f, 0.f, 0.f, 0.f};
#pragma unroll
    for (int kk = 0; kk < 4; ++kk) {
        int k0 = kk * 32 + kg * 8;
        v8bf a = *reinterpret_cast<const v8bf*>(&Xs[w * 16 + lr16][k0]);
#pragma unroll
        for (int n = 0; n < 8; ++n) {
            v8bf b = *reinterpret_cast<const v8bf*>(&Ws[n * 16 + lr16][k0]);
            acc[n] = __builtin_amdgcn_mfma_f32_16x16x32_bf16(a, b, acc[n], 0, 0, 0);
        }
    }
#pragma unroll
    for (int n = 0; n < 8; ++n)
        for (int j = 0; j < 4; ++j) {
            int slot = w * 16 + kg * 4 + j;
            int col  = n * 16 + lr16;
            float v  = acc[n][j] * nrm_l[slot];
            atomicAdd(&tmp[(size_t)dst_l[slot] * HH + col], v);
        }
}

// ---------------- BN: column sums ----------------
__global__ void k_bnsum(const float* __restrict__ tmp, float* __restrict__ sums,
                        float* __restrict__ sumsq) {
    int col = threadIdx.x & 127;
    int half = threadIdx.x >> 7;
    int base = blockIdx.x * 512;
    float s = 0.f, s2 = 0.f;
    for (int r = half; r < 512; r += 2) {
        int row = base + r;
        if (row < NN) {
            float v = tmp[(size_t)row * HH + col];
            s += v; s2 += v * v;
        }
    }
    __shared__ float sh[2][128], sh2[2][128];
    sh[half][col] = s; sh2[half][col] = s2;
    __syncthreads();
    if (half == 0) {
        atomicAdd(&sums[col], s + sh[1][col]);
        atomicAdd(&sumsq[col], s2 + sh2[1][col]);
    }
}

// ---------------- BN apply + ReLU ----------------
__global__ void k_bnapply(const float* __restrict__ tmp, const float* __restrict__ sums,
                          const float* __restrict__ sumsq, const float* __restrict__ g,
                          const float* __restrict__ be, unsigned short* __restrict__ hout,
                          float* __restrict__ fout, int write_bf16) {
    int idx = blockIdx.x * blockDim.x + threadIdx.x;
    if (idx >= NN * HH) return;
    int col = idx & 127;
    float inv_n = 1.0f / (float)NN;
    float mean = sums[col] * inv_n;
    float var = sumsq[col] * inv_n - mean * mean;
    float sc = g[col] * rsqrtf(var + BN_EPS);
    float v = (tmp[idx] - mean) * sc + be[col];
    v = fmaxf(v, 0.f);
    if (write_bf16) hout[idx] = f2b(v);
    else fout[idx] = v;
}

// ---------------- workspace layout ----------------
constexpr size_t OFF_DEG  = 0;                                    // N*R*4 = 12,000,000
constexpr size_t OFF_HB   = OFF_DEG + (size_t)NN * RR * 4;        // N*H*2
constexpr size_t OFF_TMP  = OFF_HB + (size_t)NN * HH * 2;         // N*H*4
constexpr size_t OFF_W1T  = OFF_TMP + (size_t)NN * HH * 4;
constexpr size_t OFF_W2T  = OFF_W1T + (size_t)RR * HH * HH * 2;
constexpr size_t OFF_R1T  = OFF_W2T + (size_t)RR * HH * HH * 2;
constexpr size_t OFF_R2T  = OFF_R1T + (size_t)HH * HH * 2;
constexpr size_t OFF_SRCS = OFF_R2T + (size_t)HH * HH * 2;
constexpr size_t OFF_DSTS = OFF_SRCS + (size_t)EPAD * 4;
constexpr size_t OFF_ETS  = OFF_DSTS + (size_t)EPAD * 4;
constexpr size_t OFF_NRMS = OFF_ETS + (size_t)EPAD * 4;
constexpr size_t OFF_CTRL = OFF_NRMS + (size_t)EPAD * 4;          // cnt[32],cursor[32],totals
constexpr size_t OFF_BNS  = OFF_CTRL + 512;
constexpr size_t OFF_BNSQ = OFF_BNS + 512;
constexpr size_t WS_NEED  = OFF_BNSQ + 512;                       // ~100.5 MB

extern "C" void kernel_launch(void* const* d_in, const int* in_sizes, int n_in,
                              void* d_out, int out_size, void* d_ws, size_t ws_size,
                              hipStream_t stream) {
    const int*   x     = (const int*)d_in[0];
    const int*   eidx  = (const int*)d_in[1];   // (2,E) row-major: src then dst
    const int*   et    = (const int*)d_in[2];
    const float* emb   = (const float*)d_in[3];
    const float* W1    = (const float*)d_in[4];
    const float* root1 = (const float*)d_in[5];
    const float* b1    = (const float*)d_in[6];
    const float* g1    = (const float*)d_in[7];
    const float* be1   = (const float*)d_in[8];
    const float* W2    = (const float*)d_in[9];
    const float* root2 = (const float*)d_in[10];
    const float* b2    = (const float*)d_in[11];
    const float* g2    = (const float*)d_in[12];
    const float* be2   = (const float*)d_in[13];
    float* out = (float*)d_out;

    if (ws_size < WS_NEED) return;  // diagnosable: out stays poisoned

    char* ws = (char*)d_ws;
    int*   deg    = (int*)(ws + OFF_DEG);
    unsigned short* hb = (unsigned short*)(ws + OFF_HB);
    float* tmp    = (float*)(ws + OFF_TMP);
    unsigned short* W1t = (unsigned short*)(ws + OFF_W1T);
    unsigned short* W2t = (unsigned short*)(ws + OFF_W2T);
    unsigned short* r1t = (unsigned short*)(ws + OFF_R1T);
    unsigned short* r2t = (unsigned short*)(ws + OFF_R2T);
    int*   src_s  = (int*)(ws + OFF_SRCS);
    int*   dst_s  = (int*)(ws + OFF_DSTS);
    int*   et_s   = (int*)(ws + OFF_ETS);
    float* norm_s = (float*)(ws + OFF_NRMS);
    int*   cnt    = (int*)(ws + OFF_CTRL);
    int*   cursor = cnt + 32;
    int*   totals = cnt + 64;
    float* bnsum  = (float*)(ws + OFF_BNS);
    float* bnsq   = (float*)(ws + OFF_BNSQ);

    const int* srcp = eidx;
    const int* dstp = eidx + NE;

    hipMemsetAsync(deg, 0, (size_t)NN * RR * 4, stream);
    hipMemsetAsync(cnt, 0, 512, stream);

    k_hist<<<(NE + 255) / 256, 256, 0, stream>>>(dstp, et, deg, cnt);
    k_scan<<<1, 256, 0, stream>>>(cnt, cursor, totals, src_s, dst_s, et_s, norm_s);
    k_scatter<<<(NE + 255) / 256, 256, 0, stream>>>(srcp, dstp, et, deg, cursor,
                                                    src_s, dst_s, et_s, norm_s);
    k_convW<<<(RR * HH * HH + 255) / 256, 256, 0, stream>>>(W1, W1t, RR * HH * HH);
    k_convW<<<(RR * HH * HH + 255) / 256, 256, 0, stream>>>(W2, W2t, RR * HH * HH);
    k_convW<<<(HH * HH + 255) / 256, 256, 0, stream>>>(root1, r1t, HH * HH);
    k_convW<<<(HH * HH + 255) / 256, 256, 0, stream>>>(root2, r2t, HH * HH);
    k_embed<<<(NN * HH + 255) / 256, 256, 0, stream>>>(x, emb, hb);

    const unsigned short* Wts[2]   = {W1t, W2t};
    const unsigned short* rts[2]   = {r1t, r2t};
    const float* biases[2] = {b1, b2};
    const float* gs[2]     = {g1, g2};
    const float* bes[2]    = {be1, be2};

    for (int layer = 0; layer < 2; ++layer) {
        hipMemsetAsync(bnsum, 0, 512, stream);
        hipMemsetAsync(bnsq, 0, 512, stream);
        k_rootgemm<<<(NN + TILE - 1) / TILE, 256, 0, stream>>>(hb, rts[layer],
                                                               biases[layer], tmp);
        k_edgegemm<<<EPAD / TILE, 256, 0, stream>>>(hb, Wts[layer], src_s, dst_s,
                                                    et_s, norm_s, totals, tmp);
        k_bnsum<<<(NN + 511) / 512, 256, 0, stream>>>(tmp, bnsum, bnsq);
        k_bnapply<<<(NN * HH + 255) / 256, 256, 0, stream>>>(tmp, bnsum, bnsq,
                                                             gs[layer], bes[layer],
                                                             hb, out, layer == 0);
    }
}

// Round 3
// 731.160 us; speedup vs baseline: 4.4523x; 1.4340x over previous
//
#include <hip/hip_runtime.h>
#include <hip/hip_bf16.h>

// Problem constants (from reference setup_inputs)
#define NN 100000
#define HH 128
#define RR 30
#define NE 600000
#define TILE 64
#define EPAD (NE + RR * TILE)
#define NB_PS ((NN + 255) / 256)   // 391 prefix-sum blocks
#define BN_EPS 1e-5f

typedef __bf16 v8bf __attribute__((ext_vector_type(8)));
typedef float  v4f  __attribute__((ext_vector_type(4)));

static __device__ __forceinline__ unsigned short f2b(float f) {
    unsigned int u = __float_as_uint(f);
    unsigned int r = (u + 0x7FFF + ((u >> 16) & 1)) >> 16;  // RNE
    return (unsigned short)r;
}

// ---------------- histogram: per-(dst,rel) degree, per-rel count, per-dst count ----
__global__ void k_hist(const int* __restrict__ dst, const int* __restrict__ et,
                       int* __restrict__ deg, int* __restrict__ cnt,
                       int* __restrict__ cnt_dst) {
    __shared__ int lh[RR];
    int t = threadIdx.x;
    if (t < RR) lh[t] = 0;
    __syncthreads();
    int i = blockIdx.x * blockDim.x + t;
    if (i < NE) {
        int d = dst[i], r = et[i];
        atomicAdd(&deg[d * RR + r], 1);   // scattered: memory-speed
        atomicAdd(&cnt_dst[d], 1);        // scattered: memory-speed
        atomicAdd(&lh[r], 1);             // LDS
    }
    __syncthreads();
    if (t < RR && lh[t]) atomicAdd(&cnt[t], lh[t]);
}

// ---------------- scan: relation chunk offsets, pad fill, rel-cursor init ----------
__global__ void k_scan(const int* __restrict__ cnt, int* __restrict__ cursor,
                       int* __restrict__ totals,
                       int* __restrict__ src_s, int* __restrict__ dst_s,
                       int* __restrict__ et_s, float* __restrict__ norm_s,
                       int* __restrict__ dpos_s) {
    __shared__ int off[RR + 1];
    if (threadIdx.x == 0) {
        int acc = 0;
        for (int r = 0; r < RR; ++r) {
            off[r] = acc;
            acc += (cnt[r] + TILE - 1) / TILE;
        }
        off[RR] = acc;
        totals[0] = acc * TILE;
    }
    __syncthreads();
    for (int r = 0; r < RR; ++r) {
        int begin = off[r] * TILE + cnt[r];
        int end   = off[r + 1] * TILE;
        for (int p = begin + (int)threadIdx.x; p < end; p += blockDim.x) {
            src_s[p] = 0; dst_s[p] = 0; et_s[p] = r; norm_s[p] = 0.f;
            dpos_s[p] = NE;  // pads dump zeros into unread row NE of xe
        }
    }
    if (threadIdx.x == 0)
        for (int r = 0; r < RR; ++r) cursor[r] = off[r] * TILE;
}

// ---------------- hierarchical prefix sum over cnt_dst (100k bins) ----------------
__global__ void k_psum1(const int* __restrict__ c, int* __restrict__ bsum) {
    __shared__ int sh[256];
    int i = blockIdx.x * 256 + threadIdx.x;
    sh[threadIdx.x] = (i < NN) ? c[i] : 0;
    __syncthreads();
    for (int s = 128; s > 0; s >>= 1) {
        if (threadIdx.x < s) sh[threadIdx.x] += sh[threadIdx.x + s];
        __syncthreads();
    }
    if (threadIdx.x == 0) bsum[blockIdx.x] = sh[0];
}

__global__ void k_psum2(int* __restrict__ bsum) {
    __shared__ int sh[512];
    int t = threadIdx.x;
    sh[t] = (t < NB_PS) ? bsum[t] : 0;
    __syncthreads();
    if (t == 0) {
        int acc = 0;
        for (int b = 0; b < NB_PS; ++b) { int v = sh[b]; sh[b] = acc; acc += v; }
    }
    __syncthreads();
    if (t < NB_PS) bsum[t] = sh[t];
}

__global__ void k_psum3(const int* __restrict__ c, const int* __restrict__ bscan,
                        int* __restrict__ off, int* __restrict__ cur) {
    __shared__ int sh[256];
    int t = threadIdx.x;
    int i = blockIdx.x * 256 + t;
    int v = (i < NN) ? c[i] : 0;
    sh[t] = v;
    __syncthreads();
    for (int s = 1; s < 256; s <<= 1) {   // Hillis-Steele inclusive scan
        int a = (t >= s) ? sh[t - s] : 0;
        __syncthreads();
        sh[t] += a;
        __syncthreads();
    }
    int excl = sh[t] - v + bscan[blockIdx.x];
    if (i < NN) { off[i] = excl; cur[i] = excl; }
    if (i == 0) off[NN] = NE;
}

// ---------------- scatter into relation-sorted arrays + dst-slot assignment -------
__global__ void k_scatter(const int* __restrict__ src, const int* __restrict__ dst,
                          const int* __restrict__ et, const int* __restrict__ deg,
                          int* __restrict__ cursor, int* __restrict__ cursor_dst,
                          int* __restrict__ src_s, int* __restrict__ dst_s,
                          int* __restrict__ et_s, float* __restrict__ norm_s,
                          int* __restrict__ dpos_s) {
    __shared__ int lh[RR];
    __shared__ int lbase[RR];
    int t = threadIdx.x;
    if (t < RR) lh[t] = 0;
    __syncthreads();
    int i = blockIdx.x * blockDim.x + t;
    int r = 0, d = 0, lrank = 0;
    bool valid = (i < NE);
    if (valid) {
        r = et[i]; d = dst[i];
        lrank = atomicAdd(&lh[r], 1);
    }
    __syncthreads();
    if (t < RR && lh[t]) lbase[t] = atomicAdd(&cursor[t], lh[t]);
    __syncthreads();
    if (valid) {
        int pos = lbase[r] + lrank;
        src_s[pos] = src[i];
        dst_s[pos] = d;
        et_s[pos]  = r;
        int dg = deg[d * RR + r];
        norm_s[pos] = 1.0f / (float)(dg > 1 ? dg : 1);
        dpos_s[pos] = atomicAdd(&cursor_dst[d], 1);  // slot in dst-sorted xe
    }
}

// ---------------- convert+transpose weights to bf16: Wt[m][c][k] = W[m][k][c] ----
__global__ void k_convW(const float* __restrict__ W, unsigned short* __restrict__ Wt,
                        int total) {
    int idx = blockIdx.x * blockDim.x + threadIdx.x;
    if (idx >= total) return;
    int m = idx / (HH * HH);
    int rem = idx % (HH * HH);
    int k = rem / HH, c = rem % HH;
    Wt[m * HH * HH + c * HH + k] = f2b(W[idx]);
}

// ---------------- embedding lookup -> bf16 h ----------------
__global__ void k_embed(const int* __restrict__ x, const float* __restrict__ emb,
                        unsigned short* __restrict__ hb) {
    int idx = blockIdx.x * blockDim.x + threadIdx.x;
    if (idx >= NN * HH) return;
    int i = idx / HH, j = idx % HH;
    hb[idx] = f2b(emb[x[i] * HH + j]);
}

// ---------------- root GEMM: tmp = h @ root + bias ----------------
__global__ __launch_bounds__(256) void k_rootgemm(const unsigned short* __restrict__ hb,
                                                  const unsigned short* __restrict__ rootT,
                                                  const float* __restrict__ bias,
                                                  float* __restrict__ tmp) {
    __shared__ __align__(16) unsigned short Xs[TILE][HH + 8];
    __shared__ __align__(16) unsigned short Ws[HH][HH + 8];
    int base = blockIdx.x * TILE;
    int t = threadIdx.x;

    {
        int l = t >> 2, lr = t & 3;
        int row = base + l;
        for (int i = 0; i < 4; ++i) {
            int g = lr + 4 * i;
            uint4 v = {0u, 0u, 0u, 0u};
            if (row < NN) v = *reinterpret_cast<const uint4*>(hb + (size_t)row * HH + g * 8);
            *reinterpret_cast<uint4*>(&Xs[l][g * 8]) = v;
        }
    }
    for (int i = 0; i < 8; ++i) {
        int idx = t + 256 * i;
        int row = idx >> 4, g = idx & 15;
        *reinterpret_cast<uint4*>(&Ws[row][g * 8]) =
            *reinterpret_cast<const uint4*>(rootT + row * HH + g * 8);
    }
    __syncthreads();

    int w = t >> 6, lane = t & 63;
    int lr16 = lane & 15, kg = lane >> 4;
    v4f acc[8];
    for (int n = 0; n < 8; ++n) acc[n] = (v4f){0.f, 0.f, 0.f, 0.f};
#pragma unroll
    for (int kk = 0; kk < 4; ++kk) {
        int k0 = kk * 32 + kg * 8;
        v8bf a = *reinterpret_cast<const v8bf*>(&Xs[w * 16 + lr16][k0]);
#pragma unroll
        for (int n = 0; n < 8; ++n) {
            v8bf b = *reinterpret_cast<const v8bf*>(&Ws[n * 16 + lr16][k0]);
            acc[n] = __builtin_amdgcn_mfma_f32_16x16x32_bf16(a, b, acc[n], 0, 0, 0);
        }
    }
#pragma unroll
    for (int n = 0; n < 8; ++n)
        for (int j = 0; j < 4; ++j) {
            int row = base + w * 16 + kg * 4 + j;
            int col = n * 16 + lr16;
            if (row < NN) tmp[(size_t)row * HH + col] = acc[n][j] + bias[col];
        }
}

// ---------------- edge GEMM -> xe rows (dst-sorted slots), no atomics ------------
__global__ __launch_bounds__(256) void k_edgegemm_x(const unsigned short* __restrict__ hb,
                                                    const unsigned short* __restrict__ Wt,
                                                    const int* __restrict__ src_s,
                                                    const int* __restrict__ et_s,
                                                    const float* __restrict__ norm_s,
                                                    const int* __restrict__ dpos_s,
                                                    const int* __restrict__ totals,
                                                    unsigned short* __restrict__ xe) {
    int ebase = blockIdx.x * TILE;
    if (ebase >= totals[0]) return;
    __shared__ __align__(16) unsigned short Xs[TILE][HH + 8];
    __shared__ __align__(16) unsigned short Ws[HH][HH + 8];
    __shared__ int   src_l[TILE];
    __shared__ int   dpos_l[TILE];
    __shared__ float nrm_l[TILE];
    int t = threadIdx.x;
    if (t < TILE) {
        src_l[t]  = src_s[ebase + t];
        dpos_l[t] = dpos_s[ebase + t];
        nrm_l[t]  = norm_s[ebase + t];
    }
    int rel = et_s[ebase];  // single-relation chunk by construction
    __syncthreads();

    {
        int l = t >> 2, lr = t & 3;
        int srow = src_l[l];
        for (int i = 0; i < 4; ++i) {
            int g = lr + 4 * i;
            *reinterpret_cast<uint4*>(&Xs[l][g * 8]) =
                *reinterpret_cast<const uint4*>(hb + (size_t)srow * HH + g * 8);
        }
    }
    const unsigned short* Wr = Wt + (size_t)rel * HH * HH;
    for (int i = 0; i < 8; ++i) {
        int idx = t + 256 * i;
        int row = idx >> 4, g = idx & 15;
        *reinterpret_cast<uint4*>(&Ws[row][g * 8]) =
            *reinterpret_cast<const uint4*>(Wr + row * HH + g * 8);
    }
    __syncthreads();

    int w = t >> 6, lane = t & 63;
    int lr16 = lane & 15, kg = lane >> 4;
    v4f acc[8];
    for (int n = 0; n < 8; ++n) acc[n] = (v4f){0.f, 0.f, 0.f, 0.f};
#pragma unroll
    for (int kk = 0; kk < 4; ++kk) {
        int k0 = kk * 32 + kg * 8;
        v8bf a = *reinterpret_cast<const v8bf*>(&Xs[w * 16 + lr16][k0]);
#pragma unroll
        for (int n = 0; n < 8; ++n) {
            v8bf b = *reinterpret_cast<const v8bf*>(&Ws[n * 16 + lr16][k0]);
            acc[n] = __builtin_amdgcn_mfma_f32_16x16x32_bf16(a, b, acc[n], 0, 0, 0);
        }
    }
    __syncthreads();  // done reading Xs/Ws; reuse Xs as bf16 output staging
#pragma unroll
    for (int n = 0; n < 8; ++n)
        for (int j = 0; j < 4; ++j) {
            int slot = w * 16 + kg * 4 + j;
            Xs[slot][n * 16 + lr16] = f2b(acc[n][j] * nrm_l[slot]);
        }
    __syncthreads();
    {
        int l = t >> 2, lr = t & 3;
        size_t drow = (size_t)dpos_l[l];
        for (int i = 0; i < 4; ++i) {
            int g = lr + 4 * i;
            *reinterpret_cast<uint4*>(xe + drow * HH + g * 8) =
                *reinterpret_cast<uint4*>(&Xs[l][g * 8]);
        }
    }
}

// ---------------- fallback: old atomic edge GEMM (if ws too small for xe) --------
__global__ __launch_bounds__(256) void k_edgegemm_at(const unsigned short* __restrict__ hb,
                                                     const unsigned short* __restrict__ Wt,
                                                     const int* __restrict__ src_s,
                                                     const int* __restrict__ dst_s,
                                                     const int* __restrict__ et_s,
                                                     const float* __restrict__ norm_s,
                                                     const int* __restrict__ totals,
                                                     float* __restrict__ tmp) {
    int ebase = blockIdx.x * TILE;
    if (ebase >= totals[0]) return;
    __shared__ __align__(16) unsigned short Xs[TILE][HH + 8];
    __shared__ __align__(16) unsigned short Ws[HH][HH + 8];
    __shared__ int   src_l[TILE];
    __shared__ int   dst_l[TILE];
    __shared__ float nrm_l[TILE];
    int t = threadIdx.x;
    if (t < TILE) {
        src_l[t] = src_s[ebase + t];
        dst_l[t] = dst_s[ebase + t];
        nrm_l[t] = norm_s[ebase + t];
    }
    int rel = et_s[ebase];
    __syncthreads();
    {
        int l = t >> 2, lr = t & 3;
        int srow = src_l[l];
        for (int i = 0; i < 4; ++i) {
            int g = lr + 4 * i;
            *reinterpret_cast<uint4*>(&Xs[l][g * 8]) =
                *reinterpret_cast<const uint4*>(hb + (size_t)srow * HH + g * 8);
        }
    }
    const unsigned short* Wr = Wt + (size_t)rel * HH * HH;
    for (int i = 0; i < 8; ++i) {
        int idx = t + 256 * i;
        int row = idx >> 4, g = idx & 15;
        *reinterpret_cast<uint4*>(&Ws[row][g * 8]) =
            *reinterpret_cast<const uint4*>(Wr + row * HH + g * 8);
    }
    __syncthreads();
    int w = t >> 6, lane = t & 63;
    int lr16 = lane & 15, kg = lane >> 4;
    v4f acc[8];
    for (int n = 0; n < 8; ++n) acc[n] = (v4f){0.f, 0.f, 0.f, 0.f};
#pragma unroll
    for (int kk = 0; kk < 4; ++kk) {
        int k0 = kk * 32 + kg * 8;
        v8bf a = *reinterpret_cast<const v8bf*>(&Xs[w * 16 + lr16][k0]);
#pragma unroll
        for (int n = 0; n < 8; ++n) {
            v8bf b = *reinterpret_cast<const v8bf*>(&Ws[n * 16 + lr16][k0]);
            acc[n] = __builtin_amdgcn_mfma_f32_16x16x32_bf16(a, b, acc[n], 0, 0, 0);
        }
    }
#pragma unroll
    for (int n = 0; n < 8; ++n)
        for (int j = 0; j < 4; ++j) {
            int slot = w * 16 + kg * 4 + j;
            int col  = n * 16 + lr16;
            atomicAdd(&tmp[(size_t)dst_l[slot] * HH + col], acc[n][j] * nrm_l[slot]);
        }
}

// ---------------- segmented sum: tmp[d] += sum of xe rows in [off[d], off[d+1]) --
__global__ void k_aggsum(const unsigned int* __restrict__ xe32,
                         const int* __restrict__ off, float* __restrict__ tmp) {
    int gw = (blockIdx.x * blockDim.x + threadIdx.x) >> 6;
    int lane = threadIdx.x & 63;
    int nw = (gridDim.x * blockDim.x) >> 6;
    for (int d = gw; d < NN; d += nw) {
        int s = off[d], e = off[d + 1];
        if (s == e) continue;
        float a0 = 0.f, a1 = 0.f;
        for (int p = s; p < e; ++p) {
            unsigned int v = xe32[(size_t)p * 64 + lane];
            a0 += __uint_as_float(v << 16);
            a1 += __uint_as_float(v & 0xffff0000u);
        }
        float2* t2 = reinterpret_cast<float2*>(tmp + (size_t)d * HH);
        float2 o = t2[lane];
        o.x += a0; o.y += a1;
        t2[lane] = o;
    }
}

// ---------------- BN: column sums ----------------
__global__ void k_bnsum(const float* __restrict__ tmp, float* __restrict__ sums,
                        float* __restrict__ sumsq) {
    int col = threadIdx.x & 127;
    int half = threadIdx.x >> 7;
    int base = blockIdx.x * 512;
    float s = 0.f, s2 = 0.f;
    for (int r = half; r < 512; r += 2) {
        int row = base + r;
        if (row < NN) {
            float v = tmp[(size_t)row * HH + col];
            s += v; s2 += v * v;
        }
    }
    __shared__ float sh[2][128], sh2[2][128];
    sh[half][col] = s; sh2[half][col] = s2;
    __syncthreads();
    if (half == 0) {
        atomicAdd(&sums[col], s + sh[1][col]);
        atomicAdd(&sumsq[col], s2 + sh2[1][col]);
    }
}

// ---------------- BN apply + ReLU ----------------
__global__ void k_bnapply(const float* __restrict__ tmp, const float* __restrict__ sums,
                          const float* __restrict__ sumsq, const float* __restrict__ g,
                          const float* __restrict__ be, unsigned short* __restrict__ hout,
                          float* __restrict__ fout, int write_bf16) {
    int idx = blockIdx.x * blockDim.x + threadIdx.x;
    if (idx >= NN * HH) return;
    int col = idx & 127;
    float inv_n = 1.0f / (float)NN;
    float mean = sums[col] * inv_n;
    float var = sumsq[col] * inv_n - mean * mean;
    float sc = g[col] * rsqrtf(var + BN_EPS);
    float v = (tmp[idx] - mean) * sc + be[col];
    v = fmaxf(v, 0.f);
    if (write_bf16) hout[idx] = f2b(v);
    else fout[idx] = v;
}

// ---------------- workspace layout (xe LAST so fallback fits small ws) -----------
constexpr size_t OFF_DEG  = 0;                                    // N*R*4
constexpr size_t OFF_HB   = OFF_DEG + (size_t)NN * RR * 4;
constexpr size_t OFF_TMP  = OFF_HB + (size_t)NN * HH * 2;
constexpr size_t OFF_W1T  = OFF_TMP + (size_t)NN * HH * 4;
constexpr size_t OFF_W2T  = OFF_W1T + (size_t)RR * HH * HH * 2;
constexpr size_t OFF_R1T  = OFF_W2T + (size_t)RR * HH * HH * 2;
constexpr size_t OFF_R2T  = OFF_R1T + (size_t)HH * HH * 2;
constexpr size_t OFF_SRCS = OFF_R2T + (size_t)HH * HH * 2;
constexpr size_t OFF_DSTS = OFF_SRCS + (size_t)EPAD * 4;
constexpr size_t OFF_ETS  = OFF_DSTS + (size_t)EPAD * 4;
constexpr size_t OFF_NRMS = OFF_ETS + (size_t)EPAD * 4;
constexpr size_t OFF_DPOS = OFF_NRMS + (size_t)EPAD * 4;
constexpr size_t OFF_CNTD = OFF_DPOS + (size_t)EPAD * 4;          // (N+1)*4
constexpr size_t OFF_OFFD = OFF_CNTD + ((size_t)(NN + 1) * 4 + 255 & ~(size_t)255);
constexpr size_t OFF_CURD = OFF_OFFD + ((size_t)(NN + 1) * 4 + 255 & ~(size_t)255);
constexpr size_t OFF_BSUM = OFF_CURD + ((size_t)NN * 4 + 255 & ~(size_t)255);
constexpr size_t OFF_CTRL = OFF_BSUM + ((size_t)NB_PS * 4 + 255 & ~(size_t)255);
constexpr size_t OFF_BNS  = OFF_CTRL + 512;
constexpr size_t OFF_BNSQ = OFF_BNS + 512;
constexpr size_t OFF_XE   = (OFF_BNSQ + 512 + 255) & ~(size_t)255;
constexpr size_t WS_MIN   = OFF_XE;                               // ~104 MB (fallback)
constexpr size_t WS_FULL  = OFF_XE + (size_t)EPAD * HH * 2;       // ~258 MB

extern "C" void kernel_launch(void* const* d_in, const int* in_sizes, int n_in,
                              void* d_out, int out_size, void* d_ws, size_t ws_size,
                              hipStream_t stream) {
    const int*   x     = (const int*)d_in[0];
    const int*   eidx  = (const int*)d_in[1];   // (2,E) row-major: src then dst
    const int*   et    = (const int*)d_in[2];
    const float* emb   = (const float*)d_in[3];
    const float* W1    = (const float*)d_in[4];
    const float* root1 = (const float*)d_in[5];
    const float* b1    = (const float*)d_in[6];
    const float* g1    = (const float*)d_in[7];
    const float* be1   = (const float*)d_in[8];
    const float* W2    = (const float*)d_in[9];
    const float* root2 = (const float*)d_in[10];
    const float* b2    = (const float*)d_in[11];
    const float* g2    = (const float*)d_in[12];
    const float* be2   = (const float*)d_in[13];
    float* out = (float*)d_out;

    if (ws_size < WS_MIN) return;  // diagnosable: out stays poisoned
    const bool full = (ws_size >= WS_FULL);

    char* ws = (char*)d_ws;
    int*   deg    = (int*)(ws + OFF_DEG);
    unsigned short* hb = (unsigned short*)(ws + OFF_HB);
    float* tmp    = (float*)(ws + OFF_TMP);
    unsigned short* W1t = (unsigned short*)(ws + OFF_W1T);
    unsigned short* W2t = (unsigned short*)(ws + OFF_W2T);
    unsigned short* r1t = (unsigned short*)(ws + OFF_R1T);
    unsigned short* r2t = (unsigned short*)(ws + OFF_R2T);
    int*   src_s  = (int*)(ws + OFF_SRCS);
    int*   dst_s  = (int*)(ws + OFF_DSTS);
    int*   et_s   = (int*)(ws + OFF_ETS);
    float* norm_s = (float*)(ws + OFF_NRMS);
    int*   dpos_s = (int*)(ws + OFF_DPOS);
    int*   cnt_d  = (int*)(ws + OFF_CNTD);
    int*   off_d  = (int*)(ws + OFF_OFFD);
    int*   cur_d  = (int*)(ws + OFF_CURD);
    int*   bsum   = (int*)(ws + OFF_BSUM);
    int*   cnt    = (int*)(ws + OFF_CTRL);
    int*   cursor = cnt + 32;
    int*   totals = cnt + 64;
    float* bnsum  = (float*)(ws + OFF_BNS);
    float* bnsq   = (float*)(ws + OFF_BNSQ);
    unsigned short* xe = (unsigned short*)(ws + OFF_XE);

    const int* srcp = eidx;
    const int* dstp = eidx + NE;

    hipMemsetAsync(deg, 0, (size_t)NN * RR * 4, stream);
    hipMemsetAsync(cnt, 0, 512, stream);
    hipMemsetAsync(cnt_d, 0, (size_t)(NN + 1) * 4, stream);

    k_hist<<<(NE + 255) / 256, 256, 0, stream>>>(dstp, et, deg, cnt, cnt_d);
    k_scan<<<1, 256, 0, stream>>>(cnt, cursor, totals, src_s, dst_s, et_s, norm_s, dpos_s);
    k_psum1<<<NB_PS, 256, 0, stream>>>(cnt_d, bsum);
    k_psum2<<<1, 512, 0, stream>>>(bsum);
    k_psum3<<<NB_PS, 256, 0, stream>>>(cnt_d, bsum, off_d, cur_d);
    k_scatter<<<(NE + 255) / 256, 256, 0, stream>>>(srcp, dstp, et, deg, cursor, cur_d,
                                                    src_s, dst_s, et_s, norm_s, dpos_s);
    k_convW<<<(RR * HH * HH + 255) / 256, 256, 0, stream>>>(W1, W1t, RR * HH * HH);
    k_convW<<<(RR * HH * HH + 255) / 256, 256, 0, stream>>>(W2, W2t, RR * HH * HH);
    k_convW<<<(HH * HH + 255) / 256, 256, 0, stream>>>(root1, r1t, HH * HH);
    k_convW<<<(HH * HH + 255) / 256, 256, 0, stream>>>(root2, r2t, HH * HH);
    k_embed<<<(NN * HH + 255) / 256, 256, 0, stream>>>(x, emb, hb);

    const unsigned short* Wts[2] = {W1t, W2t};
    const unsigned short* rts[2] = {r1t, r2t};
    const float* biases[2] = {b1, b2};
    const float* gs[2]     = {g1, g2};
    const float* bes[2]    = {be1, be2};

    for (int layer = 0; layer < 2; ++layer) {
        hipMemsetAsync(bnsum, 0, 512, stream);
        hipMemsetAsync(bnsq, 0, 512, stream);
        k_rootgemm<<<(NN + TILE - 1) / TILE, 256, 0, stream>>>(hb, rts[layer],
                                                               biases[layer], tmp);
        if (full) {
            k_edgegemm_x<<<EPAD / TILE, 256, 0, stream>>>(hb, Wts[layer], src_s, et_s,
                                                          norm_s, dpos_s, totals, xe);
            k_aggsum<<<1024, 256, 0, stream>>>((const unsigned int*)xe, off_d, tmp);
        } else {
            k_edgegemm_at<<<EPAD / TILE, 256, 0, stream>>>(hb, Wts[layer], src_s, dst_s,
                                                           et_s, norm_s, totals, tmp);
        }
        k_bnsum<<<(NN + 511) / 512, 256, 0, stream>>>(tmp, bnsum, bnsq);
        k_bnapply<<<(NN * HH + 255) / 256, 256, 0, stream>>>(tmp, bnsum, bnsq,
                                                             gs[layer], bes[layer],
                                                             hb, out, layer == 0);
    }
}

// Round 4
// 688.119 us; speedup vs baseline: 4.7308x; 1.0625x over previous
//
#include <hip/hip_runtime.h>
#include <hip/hip_bf16.h>

// Problem constants (from reference setup_inputs)
#define NN 100000
#define HH 128
#define RR 30
#define NE 600000
#define TILE 64
#define CH 64                       // aggseg chunk rows (NE % CH == 0)
#define EPAD (NE + RR * TILE)
#define NB_PS ((NN + 255) / 256)    // 391 prefix-sum blocks
#define BN_EPS 1e-5f

typedef __bf16 v8bf __attribute__((ext_vector_type(8)));
typedef float  v4f  __attribute__((ext_vector_type(4)));

static __device__ __forceinline__ unsigned short f2b(float f) {
    unsigned int u = __float_as_uint(f);
    unsigned int r = (u + 0x7FFF + ((u >> 16) & 1)) >> 16;  // RNE
    return (unsigned short)r;
}

// ---------------- histogram: per-(dst,rel) degree, per-rel count, per-dst count ----
__global__ void k_hist(const int* __restrict__ dst, const int* __restrict__ et,
                       int* __restrict__ deg, int* __restrict__ cnt,
                       int* __restrict__ cnt_dst) {
    __shared__ int lh[RR];
    int t = threadIdx.x;
    if (t < RR) lh[t] = 0;
    __syncthreads();
    int i = blockIdx.x * blockDim.x + t;
    if (i < NE) {
        int d = dst[i], r = et[i];
        atomicAdd(&deg[d * RR + r], 1);   // scattered: memory-speed
        atomicAdd(&cnt_dst[d], 1);        // scattered: memory-speed
        atomicAdd(&lh[r], 1);             // LDS
    }
    __syncthreads();
    if (t < RR && lh[t]) atomicAdd(&cnt[t], lh[t]);
}

// ---------------- scan: relation chunk offsets, pad fill, rel-cursor init ----------
__global__ void k_scan(const int* __restrict__ cnt, int* __restrict__ cursor,
                       int* __restrict__ totals,
                       int* __restrict__ src_s, int* __restrict__ dst_s,
                       int* __restrict__ et_s, float* __restrict__ norm_s,
                       int* __restrict__ dpos_s) {
    __shared__ int off[RR + 1];
    if (threadIdx.x == 0) {
        int acc = 0;
        for (int r = 0; r < RR; ++r) {
            off[r] = acc;
            acc += (cnt[r] + TILE - 1) / TILE;
        }
        off[RR] = acc;
        totals[0] = acc * TILE;
    }
    __syncthreads();
    for (int r = 0; r < RR; ++r) {
        int begin = off[r] * TILE + cnt[r];
        int end   = off[r + 1] * TILE;
        for (int p = begin + (int)threadIdx.x; p < end; p += blockDim.x) {
            src_s[p] = 0; dst_s[p] = 0; et_s[p] = r; norm_s[p] = 0.f;
            dpos_s[p] = NE;  // pads dump zeros into unread row NE of xe
        }
    }
    if (threadIdx.x == 0)
        for (int r = 0; r < RR; ++r) cursor[r] = off[r] * TILE;
}

// ---------------- hierarchical prefix sum over cnt_dst (100k bins) ----------------
__global__ void k_psum1(const int* __restrict__ c, int* __restrict__ bsum) {
    __shared__ int sh[256];
    int i = blockIdx.x * 256 + threadIdx.x;
    sh[threadIdx.x] = (i < NN) ? c[i] : 0;
    __syncthreads();
    for (int s = 128; s > 0; s >>= 1) {
        if (threadIdx.x < s) sh[threadIdx.x] += sh[threadIdx.x + s];
        __syncthreads();
    }
    if (threadIdx.x == 0) bsum[blockIdx.x] = sh[0];
}

__global__ void k_psum2(int* __restrict__ bsum) {
    __shared__ int sh[512];
    int t = threadIdx.x;
    sh[t] = (t < NB_PS) ? bsum[t] : 0;
    __syncthreads();
    if (t == 0) {
        int acc = 0;
        for (int b = 0; b < NB_PS; ++b) { int v = sh[b]; sh[b] = acc; acc += v; }
    }
    __syncthreads();
    if (t < NB_PS) bsum[t] = sh[t];
}

__global__ void k_psum3(const int* __restrict__ c, const int* __restrict__ bscan,
                        int* __restrict__ off, int* __restrict__ cur) {
    __shared__ int sh[256];
    int t = threadIdx.x;
    int i = blockIdx.x * 256 + t;
    int v = (i < NN) ? c[i] : 0;
    sh[t] = v;
    __syncthreads();
    for (int s = 1; s < 256; s <<= 1) {   // Hillis-Steele inclusive scan
        int a = (t >= s) ? sh[t - s] : 0;
        __syncthreads();
        sh[t] += a;
        __syncthreads();
    }
    int excl = sh[t] - v + bscan[blockIdx.x];
    if (i < NN) { off[i] = excl; cur[i] = excl; }
    if (i == 0) off[NN] = NE;
}

// ---------------- scatter into relation-sorted arrays + dst-slot assignment -------
__global__ void k_scatter(const int* __restrict__ src, const int* __restrict__ dst,
                          const int* __restrict__ et, const int* __restrict__ deg,
                          int* __restrict__ cursor, int* __restrict__ cursor_dst,
                          int* __restrict__ src_s, int* __restrict__ dst_s,
                          int* __restrict__ et_s, float* __restrict__ norm_s,
                          int* __restrict__ dpos_s, int* __restrict__ ds2) {
    __shared__ int lh[RR];
    __shared__ int lbase[RR];
    int t = threadIdx.x;
    if (t < RR) lh[t] = 0;
    __syncthreads();
    int i = blockIdx.x * blockDim.x + t;
    int r = 0, d = 0, lrank = 0;
    bool valid = (i < NE);
    if (valid) {
        r = et[i]; d = dst[i];
        lrank = atomicAdd(&lh[r], 1);
    }
    __syncthreads();
    if (t < RR && lh[t]) lbase[t] = atomicAdd(&cursor[t], lh[t]);
    __syncthreads();
    if (valid) {
        int pos = lbase[r] + lrank;
        src_s[pos] = src[i];
        dst_s[pos] = d;
        et_s[pos]  = r;
        int dg = deg[d * RR + r];
        norm_s[pos] = 1.0f / (float)(dg > 1 ? dg : 1);
        int dp = atomicAdd(&cursor_dst[d], 1);  // slot in dst-sorted xe
        dpos_s[pos] = dp;
        ds2[dp] = d;                            // dst id per dst-sorted slot
    }
}

// ---------------- convert+transpose weights to bf16: Wt[m][c][k] = W[m][k][c] ----
__global__ void k_convW(const float* __restrict__ W, unsigned short* __restrict__ Wt,
                        int total) {
    int idx = blockIdx.x * blockDim.x + threadIdx.x;
    if (idx >= total) return;
    int m = idx / (HH * HH);
    int rem = idx % (HH * HH);
    int k = rem / HH, c = rem % HH;
    Wt[m * HH * HH + c * HH + k] = f2b(W[idx]);
}

// ---------------- embedding lookup -> bf16 h ----------------
__global__ void k_embed(const int* __restrict__ x, const float* __restrict__ emb,
                        unsigned short* __restrict__ hb) {
    int idx = blockIdx.x * blockDim.x + threadIdx.x;
    if (idx >= NN * HH) return;
    int i = idx / HH, j = idx % HH;
    hb[idx] = f2b(emb[x[i] * HH + j]);
}

// ---------------- root GEMM: tmp = h @ root + bias ----------------
__global__ __launch_bounds__(256) void k_rootgemm(const unsigned short* __restrict__ hb,
                                                  const unsigned short* __restrict__ rootT,
                                                  const float* __restrict__ bias,
                                                  float* __restrict__ tmp) {
    __shared__ __align__(16) unsigned short Xs[TILE][HH + 8];
    __shared__ __align__(16) unsigned short Ws[HH][HH + 8];
    int base = blockIdx.x * TILE;
    int t = threadIdx.x;

    {
        int l = t >> 2, lr = t & 3;
        int row = base + l;
        for (int i = 0; i < 4; ++i) {
            int g = lr + 4 * i;
            uint4 v = {0u, 0u, 0u, 0u};
            if (row < NN) v = *reinterpret_cast<const uint4*>(hb + (size_t)row * HH + g * 8);
            *reinterpret_cast<uint4*>(&Xs[l][g * 8]) = v;
        }
    }
    for (int i = 0; i < 8; ++i) {
        int idx = t + 256 * i;
        int row = idx >> 4, g = idx & 15;
        *reinterpret_cast<uint4*>(&Ws[row][g * 8]) =
            *reinterpret_cast<const uint4*>(rootT + row * HH + g * 8);
    }
    __syncthreads();

    int w = t >> 6, lane = t & 63;
    int lr16 = lane & 15, kg = lane >> 4;
    v4f acc[8];
    for (int n = 0; n < 8; ++n) acc[n] = (v4f){0.f, 0.f, 0.f, 0.f};
#pragma unroll
    for (int kk = 0; kk < 4; ++kk) {
        int k0 = kk * 32 + kg * 8;
        v8bf a = *reinterpret_cast<const v8bf*>(&Xs[w * 16 + lr16][k0]);
#pragma unroll
        for (int n = 0; n < 8; ++n) {
            v8bf b = *reinterpret_cast<const v8bf*>(&Ws[n * 16 + lr16][k0]);
            acc[n] = __builtin_amdgcn_mfma_f32_16x16x32_bf16(a, b, acc[n], 0, 0, 0);
        }
    }
#pragma unroll
    for (int n = 0; n < 8; ++n)
        for (int j = 0; j < 4; ++j) {
            int row = base + w * 16 + kg * 4 + j;
            int col = n * 16 + lr16;
            if (row < NN) tmp[(size_t)row * HH + col] = acc[n][j] + bias[col];
        }
}

// ---------------- edge GEMM -> xe rows (dst-sorted slots), no atomics ------------
__global__ __launch_bounds__(256) void k_edgegemm_x(const unsigned short* __restrict__ hb,
                                                    const unsigned short* __restrict__ Wt,
                                                    const int* __restrict__ src_s,
                                                    const int* __restrict__ et_s,
                                                    const float* __restrict__ norm_s,
                                                    const int* __restrict__ dpos_s,
                                                    const int* __restrict__ totals,
                                                    unsigned short* __restrict__ xe) {
    int ebase = blockIdx.x * TILE;
    if (ebase >= totals[0]) return;
    __shared__ __align__(16) unsigned short Xs[TILE][HH + 8];
    __shared__ __align__(16) unsigned short Ws[HH][HH + 8];
    __shared__ int   src_l[TILE];
    __shared__ int   dpos_l[TILE];
    __shared__ float nrm_l[TILE];
    int t = threadIdx.x;
    if (t < TILE) {
        src_l[t]  = src_s[ebase + t];
        dpos_l[t] = dpos_s[ebase + t];
        nrm_l[t]  = norm_s[ebase + t];
    }
    int rel = et_s[ebase];  // single-relation chunk by construction
    __syncthreads();

    {
        int l = t >> 2, lr = t & 3;
        int srow = src_l[l];
        for (int i = 0; i < 4; ++i) {
            int g = lr + 4 * i;
            *reinterpret_cast<uint4*>(&Xs[l][g * 8]) =
                *reinterpret_cast<const uint4*>(hb + (size_t)srow * HH + g * 8);
        }
    }
    const unsigned short* Wr = Wt + (size_t)rel * HH * HH;
    for (int i = 0; i < 8; ++i) {
        int idx = t + 256 * i;
        int row = idx >> 4, g = idx & 15;
        *reinterpret_cast<uint4*>(&Ws[row][g * 8]) =
            *reinterpret_cast<const uint4*>(Wr + row * HH + g * 8);
    }
    __syncthreads();

    int w = t >> 6, lane = t & 63;
    int lr16 = lane & 15, kg = lane >> 4;
    v4f acc[8];
    for (int n = 0; n < 8; ++n) acc[n] = (v4f){0.f, 0.f, 0.f, 0.f};
#pragma unroll
    for (int kk = 0; kk < 4; ++kk) {
        int k0 = kk * 32 + kg * 8;
        v8bf a = *reinterpret_cast<const v8bf*>(&Xs[w * 16 + lr16][k0]);
#pragma unroll
        for (int n = 0; n < 8; ++n) {
            v8bf b = *reinterpret_cast<const v8bf*>(&Ws[n * 16 + lr16][k0]);
            acc[n] = __builtin_amdgcn_mfma_f32_16x16x32_bf16(a, b, acc[n], 0, 0, 0);
        }
    }
    __syncthreads();  // done reading Xs/Ws; reuse Xs as bf16 output staging
#pragma unroll
    for (int n = 0; n < 8; ++n)
        for (int j = 0; j < 4; ++j) {
            int slot = w * 16 + kg * 4 + j;
            Xs[slot][n * 16 + lr16] = f2b(acc[n][j] * nrm_l[slot]);
        }
    __syncthreads();
    {
        int l = t >> 2, lr = t & 3;
        size_t drow = (size_t)dpos_l[l];
        for (int i = 0; i < 4; ++i) {
            int g = lr + 4 * i;
            *reinterpret_cast<uint4*>(xe + drow * HH + g * 8) =
                *reinterpret_cast<uint4*>(&Xs[l][g * 8]);
        }
    }
}

// ---------------- fallback: atomic edge GEMM (if ws too small for xe) ------------
__global__ __launch_bounds__(256) void k_edgegemm_at(const unsigned short* __restrict__ hb,
                                                     const unsigned short* __restrict__ Wt,
                                                     const int* __restrict__ src_s,
                                                     const int* __restrict__ dst_s,
                                                     const int* __restrict__ et_s,
                                                     const float* __restrict__ norm_s,
                                                     const int* __restrict__ totals,
                                                     float* __restrict__ tmp) {
    int ebase = blockIdx.x * TILE;
    if (ebase >= totals[0]) return;
    __shared__ __align__(16) unsigned short Xs[TILE][HH + 8];
    __shared__ __align__(16) unsigned short Ws[HH][HH + 8];
    __shared__ int   src_l[TILE];
    __shared__ int   dst_l[TILE];
    __shared__ float nrm_l[TILE];
    int t = threadIdx.x;
    if (t < TILE) {
        src_l[t] = src_s[ebase + t];
        dst_l[t] = dst_s[ebase + t];
        nrm_l[t] = norm_s[ebase + t];
    }
    int rel = et_s[ebase];
    __syncthreads();
    {
        int l = t >> 2, lr = t & 3;
        int srow = src_l[l];
        for (int i = 0; i < 4; ++i) {
            int g = lr + 4 * i;
            *reinterpret_cast<uint4*>(&Xs[l][g * 8]) =
                *reinterpret_cast<const uint4*>(hb + (size_t)srow * HH + g * 8);
        }
    }
    const unsigned short* Wr = Wt + (size_t)rel * HH * HH;
    for (int i = 0; i < 8; ++i) {
        int idx = t + 256 * i;
        int row = idx >> 4, g = idx & 15;
        *reinterpret_cast<uint4*>(&Ws[row][g * 8]) =
            *reinterpret_cast<const uint4*>(Wr + row * HH + g * 8);
    }
    __syncthreads();
    int w = t >> 6, lane = t & 63;
    int lr16 = lane & 15, kg = lane >> 4;
    v4f acc[8];
    for (int n = 0; n < 8; ++n) acc[n] = (v4f){0.f, 0.f, 0.f, 0.f};
#pragma unroll
    for (int kk = 0; kk < 4; ++kk) {
        int k0 = kk * 32 + kg * 8;
        v8bf a = *reinterpret_cast<const v8bf*>(&Xs[w * 16 + lr16][k0]);
#pragma unroll
        for (int n = 0; n < 8; ++n) {
            v8bf b = *reinterpret_cast<const v8bf*>(&Ws[n * 16 + lr16][k0]);
            acc[n] = __builtin_amdgcn_mfma_f32_16x16x32_bf16(a, b, acc[n], 0, 0, 0);
        }
    }
#pragma unroll
    for (int n = 0; n < 8; ++n)
        for (int j = 0; j < 4; ++j) {
            int slot = w * 16 + kg * 4 + j;
            int col  = n * 16 + lr16;
            atomicAdd(&tmp[(size_t)dst_l[slot] * HH + col], acc[n][j] * nrm_l[slot]);
        }
}

// ---------------- chunked coalesced segmented reduce over dst-sorted xe ----------
static __device__ __forceinline__ void flushseg(int d, float a0, float a1,
                                                int c0, int c1,
                                                const int* __restrict__ off,
                                                float* __restrict__ tmp, int lane) {
    int s = off[d], e = off[d + 1];
    float* base = tmp + (size_t)d * HH + lane * 2;
    if (s >= c0 && e <= c1) {                 // segment private to this chunk
        float2* b2 = reinterpret_cast<float2*>(base);
        float2 o = *b2; o.x += a0; o.y += a1; *b2 = o;
    } else {                                  // spans chunk boundary -> atomic
        atomicAdd(base, a0);
        atomicAdd(base + 1, a1);
    }
}

__global__ __launch_bounds__(256) void k_aggseg(const unsigned int* __restrict__ xe32,
                                                const int* __restrict__ ds2,
                                                const int* __restrict__ off,
                                                float* __restrict__ tmp) {
    int wid = (blockIdx.x * blockDim.x + threadIdx.x) >> 6;
    int lane = threadIdx.x & 63;
    if (wid >= NE / CH) return;               // NE % CH == 0: all chunks full
    int c0 = wid * CH;

    // segment-boundary mask for this chunk, built once, kept in registers
    int dme = ds2[c0 + lane];
    int dpre = __shfl_up(dme, 1);
    if (lane == 0) dpre = (c0 == 0) ? -1 : ds2[c0 - 1];
    unsigned long long bmask = __ballot(dme != dpre);

    int dcur = __shfl(dme, 0);
    float a0 = 0.f, a1 = 0.f;
    for (int q0 = 0; q0 < CH; q0 += 8) {
        unsigned int v[8];
#pragma unroll
        for (int j = 0; j < 8; ++j)
            v[j] = xe32[(size_t)(c0 + q0 + j) * 64 + lane];
#pragma unroll
        for (int j = 0; j < 8; ++j) {
            int q = q0 + j;
            if (q && ((bmask >> q) & 1ull)) {
                flushseg(dcur, a0, a1, c0, c0 + CH, off, tmp, lane);
                a0 = 0.f; a1 = 0.f;
                dcur = __shfl(dme, q);
            }
            a0 += __uint_as_float(v[j] << 16);
            a1 += __uint_as_float(v[j] & 0xffff0000u);
        }
    }
    flushseg(dcur, a0, a1, c0, c0 + CH, off, tmp, lane);
}

// ---------------- BN: column sums ----------------
__global__ void k_bnsum(const float* __restrict__ tmp, float* __restrict__ sums,
                        float* __restrict__ sumsq) {
    int col = threadIdx.x & 127;
    int half = threadIdx.x >> 7;
    int base = blockIdx.x * 512;
    float s = 0.f, s2 = 0.f;
    for (int r = half; r < 512; r += 2) {
        int row = base + r;
        if (row < NN) {
            float v = tmp[(size_t)row * HH + col];
            s += v; s2 += v * v;
        }
    }
    __shared__ float sh[2][128], sh2[2][128];
    sh[half][col] = s; sh2[half][col] = s2;
    __syncthreads();
    if (half == 0) {
        atomicAdd(&sums[col], s + sh[1][col]);
        atomicAdd(&sumsq[col], s2 + sh2[1][col]);
    }
}

// ---------------- BN apply + ReLU ----------------
__global__ void k_bnapply(const float* __restrict__ tmp, const float* __restrict__ sums,
                          const float* __restrict__ sumsq, const float* __restrict__ g,
                          const float* __restrict__ be, unsigned short* __restrict__ hout,
                          float* __restrict__ fout, int write_bf16) {
    int idx = blockIdx.x * blockDim.x + threadIdx.x;
    if (idx >= NN * HH) return;
    int col = idx & 127;
    float inv_n = 1.0f / (float)NN;
    float mean = sums[col] * inv_n;
    float var = sumsq[col] * inv_n - mean * mean;
    float sc = g[col] * rsqrtf(var + BN_EPS);
    float v = (tmp[idx] - mean) * sc + be[col];
    v = fmaxf(v, 0.f);
    if (write_bf16) hout[idx] = f2b(v);
    else fout[idx] = v;
}

// ---------------- workspace layout (xe LAST so fallback fits small ws) -----------
constexpr size_t OFF_DEG  = 0;                                    // N*R*4
constexpr size_t OFF_HB   = OFF_DEG + (size_t)NN * RR * 4;
constexpr size_t OFF_TMP  = OFF_HB + (size_t)NN * HH * 2;
constexpr size_t OFF_W1T  = OFF_TMP + (size_t)NN * HH * 4;
constexpr size_t OFF_W2T  = OFF_W1T + (size_t)RR * HH * HH * 2;
constexpr size_t OFF_R1T  = OFF_W2T + (size_t)RR * HH * HH * 2;
constexpr size_t OFF_R2T  = OFF_R1T + (size_t)HH * HH * 2;
constexpr size_t OFF_SRCS = OFF_R2T + (size_t)HH * HH * 2;
constexpr size_t OFF_DSTS = OFF_SRCS + (size_t)EPAD * 4;
constexpr size_t OFF_ETS  = OFF_DSTS + (size_t)EPAD * 4;
constexpr size_t OFF_NRMS = OFF_ETS + (size_t)EPAD * 4;
constexpr size_t OFF_DPOS = OFF_NRMS + (size_t)EPAD * 4;
constexpr size_t OFF_DS2  = OFF_DPOS + (size_t)EPAD * 4;          // dst per sorted slot
constexpr size_t OFF_CNTD = OFF_DS2 + (size_t)EPAD * 4;           // (N+1)*4
constexpr size_t OFF_OFFD = OFF_CNTD + ((size_t)(NN + 1) * 4 + 255 & ~(size_t)255);
constexpr size_t OFF_CURD = OFF_OFFD + ((size_t)(NN + 1) * 4 + 255 & ~(size_t)255);
constexpr size_t OFF_BSUM = OFF_CURD + ((size_t)NN * 4 + 255 & ~(size_t)255);
constexpr size_t OFF_CTRL = OFF_BSUM + ((size_t)NB_PS * 4 + 255 & ~(size_t)255);
constexpr size_t OFF_BNS  = OFF_CTRL + 512;
constexpr size_t OFF_BNSQ = OFF_BNS + 512;
constexpr size_t OFF_XE   = (OFF_BNSQ + 512 + 255) & ~(size_t)255;
constexpr size_t WS_MIN   = OFF_XE;                               // ~107 MB (fallback)
constexpr size_t WS_FULL  = OFF_XE + (size_t)EPAD * HH * 2;       // ~261 MB

extern "C" void kernel_launch(void* const* d_in, const int* in_sizes, int n_in,
                              void* d_out, int out_size, void* d_ws, size_t ws_size,
                              hipStream_t stream) {
    const int*   x     = (const int*)d_in[0];
    const int*   eidx  = (const int*)d_in[1];   // (2,E) row-major: src then dst
    const int*   et    = (const int*)d_in[2];
    const float* emb   = (const float*)d_in[3];
    const float* W1    = (const float*)d_in[4];
    const float* root1 = (const float*)d_in[5];
    const float* b1    = (const float*)d_in[6];
    const float* g1    = (const float*)d_in[7];
    const float* be1   = (const float*)d_in[8];
    const float* W2    = (const float*)d_in[9];
    const float* root2 = (const float*)d_in[10];
    const float* b2    = (const float*)d_in[11];
    const float* g2    = (const float*)d_in[12];
    const float* be2   = (const float*)d_in[13];
    float* out = (float*)d_out;

    if (ws_size < WS_MIN) return;  // diagnosable: out stays poisoned
    const bool full = (ws_size >= WS_FULL);

    char* ws = (char*)d_ws;
    int*   deg    = (int*)(ws + OFF_DEG);
    unsigned short* hb = (unsigned short*)(ws + OFF_HB);
    float* tmp    = (float*)(ws + OFF_TMP);
    unsigned short* W1t = (unsigned short*)(ws + OFF_W1T);
    unsigned short* W2t = (unsigned short*)(ws + OFF_W2T);
    unsigned short* r1t = (unsigned short*)(ws + OFF_R1T);
    unsigned short* r2t = (unsigned short*)(ws + OFF_R2T);
    int*   src_s  = (int*)(ws + OFF_SRCS);
    int*   dst_s  = (int*)(ws + OFF_DSTS);
    int*   et_s   = (int*)(ws + OFF_ETS);
    float* norm_s = (float*)(ws + OFF_NRMS);
    int*   dpos_s = (int*)(ws + OFF_DPOS);
    int*   ds2    = (int*)(ws + OFF_DS2);
    int*   cnt_d  = (int*)(ws + OFF_CNTD);
    int*   off_d  = (int*)(ws + OFF_OFFD);
    int*   cur_d  = (int*)(ws + OFF_CURD);
    int*   bsum   = (int*)(ws + OFF_BSUM);
    int*   cnt    = (int*)(ws + OFF_CTRL);
    int*   cursor = cnt + 32;
    int*   totals = cnt + 64;
    float* bnsum  = (float*)(ws + OFF_BNS);
    float* bnsq   = (float*)(ws + OFF_BNSQ);
    unsigned short* xe = (unsigned short*)(ws + OFF_XE);

    const int* srcp = eidx;
    const int* dstp = eidx + NE;

    hipMemsetAsync(deg, 0, (size_t)NN * RR * 4, stream);
    hipMemsetAsync(cnt, 0, 512, stream);
    hipMemsetAsync(cnt_d, 0, (size_t)(NN + 1) * 4, stream);

    k_hist<<<(NE + 255) / 256, 256, 0, stream>>>(dstp, et, deg, cnt, cnt_d);
    k_scan<<<1, 256, 0, stream>>>(cnt, cursor, totals, src_s, dst_s, et_s, norm_s, dpos_s);
    k_psum1<<<NB_PS, 256, 0, stream>>>(cnt_d, bsum);
    k_psum2<<<1, 512, 0, stream>>>(bsum);
    k_psum3<<<NB_PS, 256, 0, stream>>>(cnt_d, bsum, off_d, cur_d);
    k_scatter<<<(NE + 255) / 256, 256, 0, stream>>>(srcp, dstp, et, deg, cursor, cur_d,
                                                    src_s, dst_s, et_s, norm_s, dpos_s, ds2);
    k_convW<<<(RR * HH * HH + 255) / 256, 256, 0, stream>>>(W1, W1t, RR * HH * HH);
    k_convW<<<(RR * HH * HH + 255) / 256, 256, 0, stream>>>(W2, W2t, RR * HH * HH);
    k_convW<<<(HH * HH + 255) / 256, 256, 0, stream>>>(root1, r1t, HH * HH);
    k_convW<<<(HH * HH + 255) / 256, 256, 0, stream>>>(root2, r2t, HH * HH);
    k_embed<<<(NN * HH + 255) / 256, 256, 0, stream>>>(x, emb, hb);

    const unsigned short* Wts[2] = {W1t, W2t};
    const unsigned short* rts[2] = {r1t, r2t};
    const float* biases[2] = {b1, b2};
    const float* gs[2]     = {g1, g2};
    const float* bes[2]    = {be1, be2};

    const int nchunks = NE / CH;                 // 9375
    for (int layer = 0; layer < 2; ++layer) {
        hipMemsetAsync(bnsum, 0, 512, stream);
        hipMemsetAsync(bnsq, 0, 512, stream);
        k_rootgemm<<<(NN + TILE - 1) / TILE, 256, 0, stream>>>(hb, rts[layer],
                                                               biases[layer], tmp);
        if (full) {
            k_edgegemm_x<<<EPAD / TILE, 256, 0, stream>>>(hb, Wts[layer], src_s, et_s,
                                                          norm_s, dpos_s, totals, xe);
            k_aggseg<<<(nchunks + 3) / 4, 256, 0, stream>>>((const unsigned int*)xe,
                                                            ds2, off_d, tmp);
        } else {
            k_edgegemm_at<<<EPAD / TILE, 256, 0, stream>>>(hb, Wts[layer], src_s, dst_s,
                                                           et_s, norm_s, totals, tmp);
        }
        k_bnsum<<<(NN + 511) / 512, 256, 0, stream>>>(tmp, bnsum, bnsq);
        k_bnapply<<<(NN * HH + 255) / 256, 256, 0, stream>>>(tmp, bnsum, bnsq,
                                                             gs[layer], bes[layer],
                                                             hb, out, layer == 0);
    }
}

// Round 5
// 582.062 us; speedup vs baseline: 5.5928x; 1.1822x over previous
//
#include <hip/hip_runtime.h>
#include <hip/hip_bf16.h>

// Problem constants (from reference setup_inputs)
#define NN 100000
#define HH 128
#define RR 30
#define NE 600000
#define TILE 64
#define CH 64                       // aggseg chunk rows (NE % CH == 0)
#define EPAD (NE + RR * TILE)
#define NB_PS ((NN + 255) / 256)    // 391 prefix-sum blocks
#define NBLK_BN 784                 // bn stage-1 blocks (128 rows each)
#define RPB_BN 128
#define BN_EPS 1e-5f

typedef __bf16 v8bf __attribute__((ext_vector_type(8)));
typedef float  v4f  __attribute__((ext_vector_type(4)));

static __device__ __forceinline__ unsigned short f2b(float f) {
    unsigned int u = __float_as_uint(f);
    unsigned int r = (u + 0x7FFF + ((u >> 16) & 1)) >> 16;  // RNE
    return (unsigned short)r;
}

// ---------------- histogram: per-(dst,rel) degree, per-rel count, per-dst count ----
__global__ void k_hist(const int* __restrict__ dst, const int* __restrict__ et,
                       int* __restrict__ deg, int* __restrict__ cnt,
                       int* __restrict__ cnt_dst) {
    __shared__ int lh[RR];
    int t = threadIdx.x;
    if (t < RR) lh[t] = 0;
    __syncthreads();
    int i = blockIdx.x * blockDim.x + t;
    if (i < NE) {
        int d = dst[i], r = et[i];
        atomicAdd(&deg[d * RR + r], 1);   // scattered: memory-speed
        atomicAdd(&cnt_dst[d], 1);        // scattered: memory-speed
        atomicAdd(&lh[r], 1);             // LDS
    }
    __syncthreads();
    if (t < RR && lh[t]) atomicAdd(&cnt[t], lh[t]);
}

// ---------------- scan: relation chunk offsets, pad fill, rel-cursor init ----------
__global__ void k_scan(const int* __restrict__ cnt, int* __restrict__ cursor,
                       int* __restrict__ totals,
                       int* __restrict__ src_s, int* __restrict__ dst_s,
                       int* __restrict__ et_s, float* __restrict__ norm_s,
                       int* __restrict__ dpos_s) {
    __shared__ int off[RR + 1];
    if (threadIdx.x == 0) {
        int acc = 0;
        for (int r = 0; r < RR; ++r) {
            off[r] = acc;
            acc += (cnt[r] + TILE - 1) / TILE;
        }
        off[RR] = acc;
        totals[0] = acc * TILE;
    }
    __syncthreads();
    for (int r = 0; r < RR; ++r) {
        int begin = off[r] * TILE + cnt[r];
        int end   = off[r + 1] * TILE;
        for (int p = begin + (int)threadIdx.x; p < end; p += blockDim.x) {
            src_s[p] = 0; dst_s[p] = 0; et_s[p] = r; norm_s[p] = 0.f;
            dpos_s[p] = NE;  // pads dump zeros into unread row NE of xe
        }
    }
    if (threadIdx.x == 0)
        for (int r = 0; r < RR; ++r) cursor[r] = off[r] * TILE;
}

// ---------------- hierarchical prefix sum over cnt_dst (100k bins) ----------------
__global__ void k_psum1(const int* __restrict__ c, int* __restrict__ bsum) {
    __shared__ int sh[256];
    int i = blockIdx.x * 256 + threadIdx.x;
    sh[threadIdx.x] = (i < NN) ? c[i] : 0;
    __syncthreads();
    for (int s = 128; s > 0; s >>= 1) {
        if (threadIdx.x < s) sh[threadIdx.x] += sh[threadIdx.x + s];
        __syncthreads();
    }
    if (threadIdx.x == 0) bsum[blockIdx.x] = sh[0];
}

__global__ void k_psum2(int* __restrict__ bsum) {
    __shared__ int sh[512];
    int t = threadIdx.x;
    sh[t] = (t < NB_PS) ? bsum[t] : 0;
    __syncthreads();
    if (t == 0) {
        int acc = 0;
        for (int b = 0; b < NB_PS; ++b) { int v = sh[b]; sh[b] = acc; acc += v; }
    }
    __syncthreads();
    if (t < NB_PS) bsum[t] = sh[t];
}

__global__ void k_psum3(const int* __restrict__ c, const int* __restrict__ bscan,
                        int* __restrict__ off, int* __restrict__ cur) {
    __shared__ int sh[256];
    int t = threadIdx.x;
    int i = blockIdx.x * 256 + t;
    int v = (i < NN) ? c[i] : 0;
    sh[t] = v;
    __syncthreads();
    for (int s = 1; s < 256; s <<= 1) {   // Hillis-Steele inclusive scan
        int a = (t >= s) ? sh[t - s] : 0;
        __syncthreads();
        sh[t] += a;
        __syncthreads();
    }
    int excl = sh[t] - v + bscan[blockIdx.x];
    if (i < NN) { off[i] = excl; cur[i] = excl; }
    if (i == 0) off[NN] = NE;
}

// ---------------- scatter into relation-sorted arrays + dst-slot assignment -------
__global__ void k_scatter(const int* __restrict__ src, const int* __restrict__ dst,
                          const int* __restrict__ et, const int* __restrict__ deg,
                          int* __restrict__ cursor, int* __restrict__ cursor_dst,
                          int* __restrict__ src_s, int* __restrict__ dst_s,
                          int* __restrict__ et_s, float* __restrict__ norm_s,
                          int* __restrict__ dpos_s, int* __restrict__ ds2) {
    __shared__ int lh[RR];
    __shared__ int lbase[RR];
    int t = threadIdx.x;
    if (t < RR) lh[t] = 0;
    __syncthreads();
    int i = blockIdx.x * blockDim.x + t;
    int r = 0, d = 0, lrank = 0;
    bool valid = (i < NE);
    if (valid) {
        r = et[i]; d = dst[i];
        lrank = atomicAdd(&lh[r], 1);
    }
    __syncthreads();
    if (t < RR && lh[t]) lbase[t] = atomicAdd(&cursor[t], lh[t]);
    __syncthreads();
    if (valid) {
        int pos = lbase[r] + lrank;
        src_s[pos] = src[i];
        dst_s[pos] = d;
        et_s[pos]  = r;
        int dg = deg[d * RR + r];
        norm_s[pos] = 1.0f / (float)(dg > 1 ? dg : 1);
        int dp = atomicAdd(&cursor_dst[d], 1);  // slot in dst-sorted xe
        dpos_s[pos] = dp;
        ds2[dp] = d;                            // dst id per dst-sorted slot
    }
}

// ---------------- convert+transpose weights to bf16: Wt[m][c][k] = W[m][k][c] ----
__global__ void k_convW(const float* __restrict__ W, unsigned short* __restrict__ Wt,
                        int total) {
    int idx = blockIdx.x * blockDim.x + threadIdx.x;
    if (idx >= total) return;
    int m = idx / (HH * HH);
    int rem = idx % (HH * HH);
    int k = rem / HH, c = rem % HH;
    Wt[m * HH * HH + c * HH + k] = f2b(W[idx]);
}

// ---------------- embedding lookup -> bf16 h ----------------
__global__ void k_embed(const int* __restrict__ x, const float* __restrict__ emb,
                        unsigned short* __restrict__ hb) {
    int idx = blockIdx.x * blockDim.x + threadIdx.x;
    if (idx >= NN * HH) return;
    int i = idx / HH, j = idx % HH;
    hb[idx] = f2b(emb[x[i] * HH + j]);
}

// ---------------- root GEMM: tmp = h @ root + bias ----------------
__global__ __launch_bounds__(256) void k_rootgemm(const unsigned short* __restrict__ hb,
                                                  const unsigned short* __restrict__ rootT,
                                                  const float* __restrict__ bias,
                                                  float* __restrict__ tmp) {
    __shared__ __align__(16) unsigned short Xs[TILE][HH + 8];
    __shared__ __align__(16) unsigned short Ws[HH][HH + 8];
    int base = blockIdx.x * TILE;
    int t = threadIdx.x;

    {
        int l = t >> 2, lr = t & 3;
        int row = base + l;
        for (int i = 0; i < 4; ++i) {
            int g = lr + 4 * i;
            uint4 v = {0u, 0u, 0u, 0u};
            if (row < NN) v = *reinterpret_cast<const uint4*>(hb + (size_t)row * HH + g * 8);
            *reinterpret_cast<uint4*>(&Xs[l][g * 8]) = v;
        }
    }
    for (int i = 0; i < 8; ++i) {
        int idx = t + 256 * i;
        int row = idx >> 4, g = idx & 15;
        *reinterpret_cast<uint4*>(&Ws[row][g * 8]) =
            *reinterpret_cast<const uint4*>(rootT + row * HH + g * 8);
    }
    __syncthreads();

    int w = t >> 6, lane = t & 63;
    int lr16 = lane & 15, kg = lane >> 4;
    v4f acc[8];
    for (int n = 0; n < 8; ++n) acc[n] = (v4f){0.f, 0.f, 0.f, 0.f};
#pragma unroll
    for (int kk = 0; kk < 4; ++kk) {
        int k0 = kk * 32 + kg * 8;
        v8bf a = *reinterpret_cast<const v8bf*>(&Xs[w * 16 + lr16][k0]);
#pragma unroll
        for (int n = 0; n < 8; ++n) {
            v8bf b = *reinterpret_cast<const v8bf*>(&Ws[n * 16 + lr16][k0]);
            acc[n] = __builtin_amdgcn_mfma_f32_16x16x32_bf16(a, b, acc[n], 0, 0, 0);
        }
    }
#pragma unroll
    for (int n = 0; n < 8; ++n)
        for (int j = 0; j < 4; ++j) {
            int row = base + w * 16 + kg * 4 + j;
            int col = n * 16 + lr16;
            if (row < NN) tmp[(size_t)row * HH + col] = acc[n][j] + bias[col];
        }
}

// ---------------- edge GEMM -> xe rows (dst-sorted slots), no atomics ------------
__global__ __launch_bounds__(256) void k_edgegemm_x(const unsigned short* __restrict__ hb,
                                                    const unsigned short* __restrict__ Wt,
                                                    const int* __restrict__ src_s,
                                                    const int* __restrict__ et_s,
                                                    const float* __restrict__ norm_s,
                                                    const int* __restrict__ dpos_s,
                                                    const int* __restrict__ totals,
                                                    unsigned short* __restrict__ xe) {
    int ebase = blockIdx.x * TILE;
    if (ebase >= totals[0]) return;
    __shared__ __align__(16) unsigned short Xs[TILE][HH + 8];
    __shared__ __align__(16) unsigned short Ws[HH][HH + 8];
    __shared__ int   src_l[TILE];
    __shared__ int   dpos_l[TILE];
    __shared__ float nrm_l[TILE];
    int t = threadIdx.x;
    if (t < TILE) {
        src_l[t]  = src_s[ebase + t];
        dpos_l[t] = dpos_s[ebase + t];
        nrm_l[t]  = norm_s[ebase + t];
    }
    int rel = et_s[ebase];  // single-relation chunk by construction
    __syncthreads();

    {
        int l = t >> 2, lr = t & 3;
        int srow = src_l[l];
        for (int i = 0; i < 4; ++i) {
            int g = lr + 4 * i;
            *reinterpret_cast<uint4*>(&Xs[l][g * 8]) =
                *reinterpret_cast<const uint4*>(hb + (size_t)srow * HH + g * 8);
        }
    }
    const unsigned short* Wr = Wt + (size_t)rel * HH * HH;
    for (int i = 0; i < 8; ++i) {
        int idx = t + 256 * i;
        int row = idx >> 4, g = idx & 15;
        *reinterpret_cast<uint4*>(&Ws[row][g * 8]) =
            *reinterpret_cast<const uint4*>(Wr + row * HH + g * 8);
    }
    __syncthreads();

    int w = t >> 6, lane = t & 63;
    int lr16 = lane & 15, kg = lane >> 4;
    v4f acc[8];
    for (int n = 0; n < 8; ++n) acc[n] = (v4f){0.f, 0.f, 0.f, 0.f};
#pragma unroll
    for (int kk = 0; kk < 4; ++kk) {
        int k0 = kk * 32 + kg * 8;
        v8bf a = *reinterpret_cast<const v8bf*>(&Xs[w * 16 + lr16][k0]);
#pragma unroll
        for (int n = 0; n < 8; ++n) {
            v8bf b = *reinterpret_cast<const v8bf*>(&Ws[n * 16 + lr16][k0]);
            acc[n] = __builtin_amdgcn_mfma_f32_16x16x32_bf16(a, b, acc[n], 0, 0, 0);
        }
    }
    __syncthreads();  // done reading Xs/Ws; reuse Xs as bf16 output staging
#pragma unroll
    for (int n = 0; n < 8; ++n)
        for (int j = 0; j < 4; ++j) {
            int slot = w * 16 + kg * 4 + j;
            Xs[slot][n * 16 + lr16] = f2b(acc[n][j] * nrm_l[slot]);
        }
    __syncthreads();
    {
        int l = t >> 2, lr = t & 3;
        size_t drow = (size_t)dpos_l[l];
        for (int i = 0; i < 4; ++i) {
            int g = lr + 4 * i;
            *reinterpret_cast<uint4*>(xe + drow * HH + g * 8) =
                *reinterpret_cast<uint4*>(&Xs[l][g * 8]);
        }
    }
}

// ---------------- fallback: atomic edge GEMM (if ws too small for xe) ------------
__global__ __launch_bounds__(256) void k_edgegemm_at(const unsigned short* __restrict__ hb,
                                                     const unsigned short* __restrict__ Wt,
                                                     const int* __restrict__ src_s,
                                                     const int* __restrict__ dst_s,
                                                     const int* __restrict__ et_s,
                                                     const float* __restrict__ norm_s,
                                                     const int* __restrict__ totals,
                                                     float* __restrict__ tmp) {
    int ebase = blockIdx.x * TILE;
    if (ebase >= totals[0]) return;
    __shared__ __align__(16) unsigned short Xs[TILE][HH + 8];
    __shared__ __align__(16) unsigned short Ws[HH][HH + 8];
    __shared__ int   src_l[TILE];
    __shared__ int   dst_l[TILE];
    __shared__ float nrm_l[TILE];
    int t = threadIdx.x;
    if (t < TILE) {
        src_l[t] = src_s[ebase + t];
        dst_l[t] = dst_s[ebase + t];
        nrm_l[t] = norm_s[ebase + t];
    }
    int rel = et_s[ebase];
    __syncthreads();
    {
        int l = t >> 2, lr = t & 3;
        int srow = src_l[l];
        for (int i = 0; i < 4; ++i) {
            int g = lr + 4 * i;
            *reinterpret_cast<uint4*>(&Xs[l][g * 8]) =
                *reinterpret_cast<const uint4*>(hb + (size_t)srow * HH + g * 8);
        }
    }
    const unsigned short* Wr = Wt + (size_t)rel * HH * HH;
    for (int i = 0; i < 8; ++i) {
        int idx = t + 256 * i;
        int row = idx >> 4, g = idx & 15;
        *reinterpret_cast<uint4*>(&Ws[row][g * 8]) =
            *reinterpret_cast<const uint4*>(Wr + row * HH + g * 8);
    }
    __syncthreads();
    int w = t >> 6, lane = t & 63;
    int lr16 = lane & 15, kg = lane >> 4;
    v4f acc[8];
    for (int n = 0; n < 8; ++n) acc[n] = (v4f){0.f, 0.f, 0.f, 0.f};
#pragma unroll
    for (int kk = 0; kk < 4; ++kk) {
        int k0 = kk * 32 + kg * 8;
        v8bf a = *reinterpret_cast<const v8bf*>(&Xs[w * 16 + lr16][k0]);
#pragma unroll
        for (int n = 0; n < 8; ++n) {
            v8bf b = *reinterpret_cast<const v8bf*>(&Ws[n * 16 + lr16][k0]);
            acc[n] = __builtin_amdgcn_mfma_f32_16x16x32_bf16(a, b, acc[n], 0, 0, 0);
        }
    }
#pragma unroll
    for (int n = 0; n < 8; ++n)
        for (int j = 0; j < 4; ++j) {
            int slot = w * 16 + kg * 4 + j;
            int col  = n * 16 + lr16;
            atomicAdd(&tmp[(size_t)dst_l[slot] * HH + col], acc[n][j] * nrm_l[slot]);
        }
}

// ---------------- chunked coalesced segmented reduce over dst-sorted xe ----------
static __device__ __forceinline__ void flushseg(int d, float a0, float a1,
                                                int c0, int c1,
                                                const int* __restrict__ off,
                                                float* __restrict__ tmp, int lane) {
    int s = off[d], e = off[d + 1];
    float* base = tmp + (size_t)d * HH + lane * 2;
    if (s >= c0 && e <= c1) {                 // segment private to this chunk
        float2* b2 = reinterpret_cast<float2*>(base);
        float2 o = *b2; o.x += a0; o.y += a1; *b2 = o;
    } else {                                  // spans chunk boundary -> atomic
        atomicAdd(base, a0);
        atomicAdd(base + 1, a1);
    }
}

__global__ __launch_bounds__(256) void k_aggseg(const unsigned int* __restrict__ xe32,
                                                const int* __restrict__ ds2,
                                                const int* __restrict__ off,
                                                float* __restrict__ tmp) {
    int wid = (blockIdx.x * blockDim.x + threadIdx.x) >> 6;
    int lane = threadIdx.x & 63;
    if (wid >= NE / CH) return;               // NE % CH == 0: all chunks full
    int c0 = wid * CH;

    // segment-boundary mask for this chunk, built once, kept in registers
    int dme = ds2[c0 + lane];
    int dpre = __shfl_up(dme, 1);
    if (lane == 0) dpre = (c0 == 0) ? -1 : ds2[c0 - 1];
    unsigned long long bmask = __ballot(dme != dpre);

    int dcur = __shfl(dme, 0);
    float a0 = 0.f, a1 = 0.f;
    for (int q0 = 0; q0 < CH; q0 += 8) {
        unsigned int v[8];
#pragma unroll
        for (int j = 0; j < 8; ++j)
            v[j] = xe32[(size_t)(c0 + q0 + j) * 64 + lane];
#pragma unroll
        for (int j = 0; j < 8; ++j) {
            int q = q0 + j;
            if (q && ((bmask >> q) & 1ull)) {
                flushseg(dcur, a0, a1, c0, c0 + CH, off, tmp, lane);
                a0 = 0.f; a1 = 0.f;
                dcur = __shfl(dme, q);
            }
            a0 += __uint_as_float(v[j] << 16);
            a1 += __uint_as_float(v[j] & 0xffff0000u);
        }
    }
    flushseg(dcur, a0, a1, c0, c0 + CH, off, tmp, lane);
}

// ---------------- BN stage 1: per-block column partial sums (no atomics) ---------
__global__ __launch_bounds__(256) void k_bnsum1(const float* __restrict__ tmp,
                                                float* __restrict__ psum,
                                                float* __restrict__ psq) {
    int t = threadIdx.x;
    int rg = t >> 5, lane = t & 31;           // 8 row-groups x 32 lanes (float4 cols)
    int base = blockIdx.x * RPB_BN;
    v4f s = {0.f, 0.f, 0.f, 0.f}, q = {0.f, 0.f, 0.f, 0.f};
#pragma unroll 4
    for (int i = 0; i < RPB_BN / 8; ++i) {
        int row = base + rg + 8 * i;
        if (row < NN) {
            v4f v = *reinterpret_cast<const v4f*>(tmp + (size_t)row * HH + lane * 4);
            s += v; q += v * v;
        }
    }
    __shared__ v4f shs[8][32], shq[8][32];
    shs[rg][lane] = s; shq[rg][lane] = q;
    __syncthreads();
    if (rg == 0) {
        v4f ts = shs[0][lane], tq = shq[0][lane];
#pragma unroll
        for (int k = 1; k < 8; ++k) { ts += shs[k][lane]; tq += shq[k][lane]; }
        int b = blockIdx.x;
#pragma unroll
        for (int j = 0; j < 4; ++j) {
            psum[(size_t)(lane * 4 + j) * NBLK_BN + b] = ts[j];
            psq [(size_t)(lane * 4 + j) * NBLK_BN + b] = tq[j];
        }
    }
}

// ---------------- BN stage 2: reduce partials, emit affine coefficients ----------
__global__ void k_bnsum2(const float* __restrict__ psum, const float* __restrict__ psq,
                         const float* __restrict__ g, const float* __restrict__ be,
                         float* __restrict__ sc_g, float* __restrict__ shf_g) {
    __shared__ float ssum[HH], ssq[HH];
    int t = threadIdx.x;
    int col = t & 127;
    const float* row = ((t < 128) ? psum : psq) + (size_t)col * NBLK_BN;
    v4f a = {0.f, 0.f, 0.f, 0.f};
    for (int i = 0; i < NBLK_BN / 4; ++i)
        a += *reinterpret_cast<const v4f*>(row + i * 4);
    float acc = a[0] + a[1] + a[2] + a[3];
    if (t < 128) ssum[col] = acc; else ssq[col] = acc;
    __syncthreads();
    if (t < 128) {
        float inv_n = 1.0f / (float)NN;
        float mean = ssum[col] * inv_n;
        float var = ssq[col] * inv_n - mean * mean;
        float sc = g[col] * rsqrtf(var + BN_EPS);
        sc_g[col] = sc;
        shf_g[col] = be[col] - mean * sc;
    }
}

// ---------------- BN apply + ReLU (vectorized float4) ----------------
__global__ void k_bnapply(const float* __restrict__ tmp, const float* __restrict__ sc_g,
                          const float* __restrict__ shf_g,
                          unsigned short* __restrict__ hout,
                          float* __restrict__ fout, int write_bf16) {
    int idx = blockIdx.x * blockDim.x + threadIdx.x;   // float4 index
    if (idx >= NN * HH / 4) return;
    int c4 = (idx & 31) * 4;                            // HH/4 = 32 quads per row
    v4f v  = *reinterpret_cast<const v4f*>(tmp + (size_t)idx * 4);
    v4f sc = *reinterpret_cast<const v4f*>(sc_g + c4);
    v4f sh = *reinterpret_cast<const v4f*>(shf_g + c4);
    v4f r;
#pragma unroll
    for (int j = 0; j < 4; ++j) r[j] = fmaxf(v[j] * sc[j] + sh[j], 0.f);
    if (write_bf16) {
        uint2 u;
        u.x = (unsigned int)f2b(r[0]) | ((unsigned int)f2b(r[1]) << 16);
        u.y = (unsigned int)f2b(r[2]) | ((unsigned int)f2b(r[3]) << 16);
        *reinterpret_cast<uint2*>(hout + (size_t)idx * 4) = u;
    } else {
        *reinterpret_cast<v4f*>(fout + (size_t)idx * 4) = r;
    }
}

// ---------------- workspace layout (xe LAST so fallback fits small ws) -----------
constexpr size_t OFF_DEG  = 0;                                    // N*R*4
constexpr size_t OFF_HB   = OFF_DEG + (size_t)NN * RR * 4;
constexpr size_t OFF_TMP  = OFF_HB + (size_t)NN * HH * 2;
constexpr size_t OFF_W1T  = OFF_TMP + (size_t)NN * HH * 4;
constexpr size_t OFF_W2T  = OFF_W1T + (size_t)RR * HH * HH * 2;
constexpr size_t OFF_R1T  = OFF_W2T + (size_t)RR * HH * HH * 2;
constexpr size_t OFF_R2T  = OFF_R1T + (size_t)HH * HH * 2;
constexpr size_t OFF_SRCS = OFF_R2T + (size_t)HH * HH * 2;
constexpr size_t OFF_DSTS = OFF_SRCS + (size_t)EPAD * 4;
constexpr size_t OFF_ETS  = OFF_DSTS + (size_t)EPAD * 4;
constexpr size_t OFF_NRMS = OFF_ETS + (size_t)EPAD * 4;
constexpr size_t OFF_DPOS = OFF_NRMS + (size_t)EPAD * 4;
constexpr size_t OFF_DS2  = OFF_DPOS + (size_t)EPAD * 4;          // dst per sorted slot
constexpr size_t OFF_CNTD = OFF_DS2 + (size_t)EPAD * 4;           // (N+1)*4
constexpr size_t OFF_OFFD = OFF_CNTD + ((size_t)(NN + 1) * 4 + 255 & ~(size_t)255);
constexpr size_t OFF_CURD = OFF_OFFD + ((size_t)(NN + 1) * 4 + 255 & ~(size_t)255);
constexpr size_t OFF_BSUM = OFF_CURD + ((size_t)NN * 4 + 255 & ~(size_t)255);
constexpr size_t OFF_CTRL = OFF_BSUM + ((size_t)NB_PS * 4 + 255 & ~(size_t)255);
constexpr size_t OFF_SC   = OFF_CTRL + 512;                       // 128 floats
constexpr size_t OFF_SHF  = OFF_SC + 512;
constexpr size_t OFF_PSUM = OFF_SHF + 512;                        // 128*NBLK_BN floats
constexpr size_t OFF_PSQ  = OFF_PSUM + (size_t)HH * NBLK_BN * 4;
constexpr size_t OFF_XE   = (OFF_PSQ + (size_t)HH * NBLK_BN * 4 + 255) & ~(size_t)255;
constexpr size_t WS_MIN   = OFF_XE;                               // ~108 MB (fallback)
constexpr size_t WS_FULL  = OFF_XE + (size_t)EPAD * HH * 2;       // ~261 MB

extern "C" void kernel_launch(void* const* d_in, const int* in_sizes, int n_in,
                              void* d_out, int out_size, void* d_ws, size_t ws_size,
                              hipStream_t stream) {
    const int*   x     = (const int*)d_in[0];
    const int*   eidx  = (const int*)d_in[1];   // (2,E) row-major: src then dst
    const int*   et    = (const int*)d_in[2];
    const float* emb   = (const float*)d_in[3];
    const float* W1    = (const float*)d_in[4];
    const float* root1 = (const float*)d_in[5];
    const float* b1    = (const float*)d_in[6];
    const float* g1    = (const float*)d_in[7];
    const float* be1   = (const float*)d_in[8];
    const float* W2    = (const float*)d_in[9];
    const float* root2 = (const float*)d_in[10];
    const float* b2    = (const float*)d_in[11];
    const float* g2    = (const float*)d_in[12];
    const float* be2   = (const float*)d_in[13];
    float* out = (float*)d_out;

    if (ws_size < WS_MIN) return;  // diagnosable: out stays poisoned
    const bool full = (ws_size >= WS_FULL);

    char* ws = (char*)d_ws;
    int*   deg    = (int*)(ws + OFF_DEG);
    unsigned short* hb = (unsigned short*)(ws + OFF_HB);
    float* tmp    = (float*)(ws + OFF_TMP);
    unsigned short* W1t = (unsigned short*)(ws + OFF_W1T);
    unsigned short* W2t = (unsigned short*)(ws + OFF_W2T);
    unsigned short* r1t = (unsigned short*)(ws + OFF_R1T);
    unsigned short* r2t = (unsigned short*)(ws + OFF_R2T);
    int*   src_s  = (int*)(ws + OFF_SRCS);
    int*   dst_s  = (int*)(ws + OFF_DSTS);
    int*   et_s   = (int*)(ws + OFF_ETS);
    float* norm_s = (float*)(ws + OFF_NRMS);
    int*   dpos_s = (int*)(ws + OFF_DPOS);
    int*   ds2    = (int*)(ws + OFF_DS2);
    int*   cnt_d  = (int*)(ws + OFF_CNTD);
    int*   off_d  = (int*)(ws + OFF_OFFD);
    int*   cur_d  = (int*)(ws + OFF_CURD);
    int*   bsum   = (int*)(ws + OFF_BSUM);
    int*   cnt    = (int*)(ws + OFF_CTRL);
    int*   cursor = cnt + 32;
    int*   totals = cnt + 64;
    float* sc_g   = (float*)(ws + OFF_SC);
    float* shf_g  = (float*)(ws + OFF_SHF);
    float* psum   = (float*)(ws + OFF_PSUM);
    float* psq    = (float*)(ws + OFF_PSQ);
    unsigned short* xe = (unsigned short*)(ws + OFF_XE);

    const int* srcp = eidx;
    const int* dstp = eidx + NE;

    hipMemsetAsync(deg, 0, (size_t)NN * RR * 4, stream);
    hipMemsetAsync(cnt, 0, 512, stream);
    hipMemsetAsync(cnt_d, 0, (size_t)(NN + 1) * 4, stream);

    k_hist<<<(NE + 255) / 256, 256, 0, stream>>>(dstp, et, deg, cnt, cnt_d);
    k_scan<<<1, 256, 0, stream>>>(cnt, cursor, totals, src_s, dst_s, et_s, norm_s, dpos_s);
    k_psum1<<<NB_PS, 256, 0, stream>>>(cnt_d, bsum);
    k_psum2<<<1, 512, 0, stream>>>(bsum);
    k_psum3<<<NB_PS, 256, 0, stream>>>(cnt_d, bsum, off_d, cur_d);
    k_scatter<<<(NE + 255) / 256, 256, 0, stream>>>(srcp, dstp, et, deg, cursor, cur_d,
                                                    src_s, dst_s, et_s, norm_s, dpos_s, ds2);
    k_convW<<<(RR * HH * HH + 255) / 256, 256, 0, stream>>>(W1, W1t, RR * HH * HH);
    k_convW<<<(RR * HH * HH + 255) / 256, 256, 0, stream>>>(W2, W2t, RR * HH * HH);
    k_convW<<<(HH * HH + 255) / 256, 256, 0, stream>>>(root1, r1t, HH * HH);
    k_convW<<<(HH * HH + 255) / 256, 256, 0, stream>>>(root2, r2t, HH * HH);
    k_embed<<<(NN * HH + 255) / 256, 256, 0, stream>>>(x, emb, hb);

    const unsigned short* Wts[2] = {W1t, W2t};
    const unsigned short* rts[2] = {r1t, r2t};
    const float* biases[2] = {b1, b2};
    const float* gs[2]     = {g1, g2};
    const float* bes[2]    = {be1, be2};

    const int nchunks = NE / CH;                 // 9375
    for (int layer = 0; layer < 2; ++layer) {
        k_rootgemm<<<(NN + TILE - 1) / TILE, 256, 0, stream>>>(hb, rts[layer],
                                                               biases[layer], tmp);
        if (full) {
            k_edgegemm_x<<<EPAD / TILE, 256, 0, stream>>>(hb, Wts[layer], src_s, et_s,
                                                          norm_s, dpos_s, totals, xe);
            k_aggseg<<<(nchunks + 3) / 4, 256, 0, stream>>>((const unsigned int*)xe,
                                                            ds2, off_d, tmp);
        } else {
            k_edgegemm_at<<<EPAD / TILE, 256, 0, stream>>>(hb, Wts[layer], src_s, dst_s,
                                                           et_s, norm_s, totals, tmp);
        }
        k_bnsum1<<<NBLK_BN, 256, 0, stream>>>(tmp, psum, psq);
        k_bnsum2<<<1, 256, 0, stream>>>(psum, psq, gs[layer], bes[layer], sc_g, shf_g);
        k_bnapply<<<(NN * HH / 4 + 255) / 256, 256, 0, stream>>>(tmp, sc_g, shf_g,
                                                                 hb, out, layer == 0);
    }
}

// Round 6
// 536.494 us; speedup vs baseline: 6.0678x; 1.0849x over previous
//
#include <hip/hip_runtime.h>
#include <hip/hip_bf16.h>

// Problem constants (from reference setup_inputs)
#define NN 100000
#define HH 128
#define RR 30
#define NE 600000
#define TILE 64
#define CH 64                       // aggseg chunk rows (NE % CH == 0)
#define EPAD (NE + RR * TILE)
#define NCHMAX (EPAD / TILE)        // max relation chunks (9405)
#define NB_PS ((NN + 255) / 256)    // 391 prefix-sum blocks
#define NBLK_BN 784                 // bn stage-1 blocks (128 rows each)
#define RPB_BN 128
#define BN_EPS 1e-5f

typedef __bf16 v8bf __attribute__((ext_vector_type(8)));
typedef float  v4f  __attribute__((ext_vector_type(4)));

static __device__ __forceinline__ unsigned short f2b(float f) {
    unsigned int u = __float_as_uint(f);
    unsigned int r = (u + 0x7FFF + ((u >> 16) & 1)) >> 16;  // RNE
    return (unsigned short)r;
}

// ---------------- histogram: per-(dst,rel) degree + per-rel count ----------------
__global__ void k_hist(const int* __restrict__ dst, const int* __restrict__ et,
                       int* __restrict__ deg, int* __restrict__ cnt) {
    __shared__ int lh[RR];
    int t = threadIdx.x;
    if (t < RR) lh[t] = 0;
    __syncthreads();
    int i = blockIdx.x * blockDim.x + t;
    if (i < NE) {
        int d = dst[i], r = et[i];
        atomicAdd(&deg[d * RR + r], 1);   // scattered: memory-speed
        atomicAdd(&lh[r], 1);             // LDS
    }
    __syncthreads();
    if (t < RR && lh[t]) atomicAdd(&cnt[t], lh[t]);
}

// ---------------- per-dst degree from deg (coalesced, replaces cnt_dst atomics) ---
__global__ void k_degsum(const int* __restrict__ deg, int* __restrict__ cnt_d) {
    int d = blockIdx.x * blockDim.x + threadIdx.x;
    if (d >= NN) return;
    int s = 0;
#pragma unroll
    for (int r = 0; r < RR; ++r) s += deg[(size_t)d * RR + r];
    cnt_d[d] = s;
}

// ---------------- scan: relation chunk offsets, pad fill, chunk_rel, cursors ------
__global__ void k_scan(const int* __restrict__ cnt, int* __restrict__ cursor,
                       int* __restrict__ totals,
                       int* __restrict__ src_s, int* __restrict__ dst_s,
                       float* __restrict__ norm_s, int* __restrict__ dpos_s,
                       int* __restrict__ chunk_rel, int need_dst) {
    __shared__ int off[RR + 1];
    if (threadIdx.x == 0) {
        int acc = 0;
        for (int r = 0; r < RR; ++r) {
            off[r] = acc;
            acc += (cnt[r] + TILE - 1) / TILE;
        }
        off[RR] = acc;
        totals[0] = acc * TILE;
    }
    __syncthreads();
    for (int r = 0; r < RR; ++r) {
        // per-chunk relation id (replaces the et_s array)
        for (int c = off[r] + (int)threadIdx.x; c < off[r + 1]; c += blockDim.x)
            chunk_rel[c] = r;
        // pad slots at tail of each relation's region
        int begin = off[r] * TILE + cnt[r];
        int end   = off[r + 1] * TILE;
        for (int p = begin + (int)threadIdx.x; p < end; p += blockDim.x) {
            src_s[p] = 0; norm_s[p] = 0.f;
            dpos_s[p] = NE;  // pads dump zeros into unread row NE of xe
            if (need_dst) dst_s[p] = 0;
        }
    }
    if (threadIdx.x == 0)
        for (int r = 0; r < RR; ++r) cursor[r] = off[r] * TILE;
}

// ---------------- hierarchical prefix sum over cnt_d (100k bins) ----------------
__global__ void k_psum1(const int* __restrict__ c, int* __restrict__ bsum) {
    __shared__ int sh[256];
    int i = blockIdx.x * 256 + threadIdx.x;
    sh[threadIdx.x] = (i < NN) ? c[i] : 0;
    __syncthreads();
    for (int s = 128; s > 0; s >>= 1) {
        if (threadIdx.x < s) sh[threadIdx.x] += sh[threadIdx.x + s];
        __syncthreads();
    }
    if (threadIdx.x == 0) bsum[blockIdx.x] = sh[0];
}

__global__ void k_psum2(int* __restrict__ bsum) {
    __shared__ int sh[512];
    int t = threadIdx.x;
    sh[t] = (t < NB_PS) ? bsum[t] : 0;
    __syncthreads();
    if (t == 0) {
        int acc = 0;
        for (int b = 0; b < NB_PS; ++b) { int v = sh[b]; sh[b] = acc; acc += v; }
    }
    __syncthreads();
    if (t < NB_PS) bsum[t] = sh[t];
}

__global__ void k_psum3(const int* __restrict__ c, const int* __restrict__ bscan,
                        int* __restrict__ off, int* __restrict__ cur) {
    __shared__ int sh[256];
    int t = threadIdx.x;
    int i = blockIdx.x * 256 + t;
    int v = (i < NN) ? c[i] : 0;
    sh[t] = v;
    __syncthreads();
    for (int s = 1; s < 256; s <<= 1) {   // Hillis-Steele inclusive scan
        int a = (t >= s) ? sh[t - s] : 0;
        __syncthreads();
        sh[t] += a;
        __syncthreads();
    }
    int excl = sh[t] - v + bscan[blockIdx.x];
    if (i < NN) { off[i] = excl; cur[i] = excl; }
    if (i == 0) off[NN] = NE;
}

// ---------------- fill ds2 from off_d (coalesced; replaces random ds2 writes) ----
__global__ void k_fillds2(const int* __restrict__ off, int* __restrict__ ds2) {
    int d = blockIdx.x * blockDim.x + threadIdx.x;
    if (d >= NN) return;
    int s = off[d], e = off[d + 1];
    for (int p = s; p < e; ++p) ds2[p] = d;
}

// ---------------- scatter into relation-sorted arrays + dst-slot assignment -------
__global__ void k_scatter(const int* __restrict__ src, const int* __restrict__ dst,
                          const int* __restrict__ et, const int* __restrict__ deg,
                          int* __restrict__ cursor, int* __restrict__ cursor_dst,
                          int* __restrict__ src_s, int* __restrict__ dst_s,
                          float* __restrict__ norm_s, int* __restrict__ dpos_s,
                          int need_dst) {
    __shared__ int lh[RR];
    __shared__ int lbase[RR];
    int t = threadIdx.x;
    if (t < RR) lh[t] = 0;
    __syncthreads();
    int i = blockIdx.x * blockDim.x + t;
    int r = 0, d = 0, lrank = 0;
    bool valid = (i < NE);
    if (valid) {
        r = et[i]; d = dst[i];
        lrank = atomicAdd(&lh[r], 1);
    }
    __syncthreads();
    if (t < RR && lh[t]) lbase[t] = atomicAdd(&cursor[t], lh[t]);
    __syncthreads();
    if (valid) {
        int pos = lbase[r] + lrank;
        src_s[pos] = src[i];
        if (need_dst) dst_s[pos] = d;
        int dg = deg[d * RR + r];
        norm_s[pos] = 1.0f / (float)(dg > 1 ? dg : 1);
        dpos_s[pos] = atomicAdd(&cursor_dst[d], 1);  // slot in dst-sorted xe
    }
}

// ---------------- convert+transpose weights to bf16: Wt[m][c][k] = W[m][k][c] ----
__global__ void k_convW(const float* __restrict__ W, unsigned short* __restrict__ Wt,
                        int total) {
    int idx = blockIdx.x * blockDim.x + threadIdx.x;
    if (idx >= total) return;
    int m = idx / (HH * HH);
    int rem = idx % (HH * HH);
    int k = rem / HH, c = rem % HH;
    Wt[m * HH * HH + c * HH + k] = f2b(W[idx]);
}

// ---------------- embedding lookup -> bf16 h ----------------
__global__ void k_embed(const int* __restrict__ x, const float* __restrict__ emb,
                        unsigned short* __restrict__ hb) {
    int idx = blockIdx.x * blockDim.x + threadIdx.x;
    if (idx >= NN * HH) return;
    int i = idx / HH, j = idx % HH;
    hb[idx] = f2b(emb[x[i] * HH + j]);
}

// ---------------- root GEMM: tmp = h @ root + bias ----------------
__global__ __launch_bounds__(256) void k_rootgemm(const unsigned short* __restrict__ hb,
                                                  const unsigned short* __restrict__ rootT,
                                                  const float* __restrict__ bias,
                                                  float* __restrict__ tmp) {
    __shared__ __align__(16) unsigned short Xs[TILE][HH + 8];
    __shared__ __align__(16) unsigned short Ws[HH][HH + 8];
    int base = blockIdx.x * TILE;
    int t = threadIdx.x;

    {
        int l = t >> 2, lr = t & 3;
        int row = base + l;
        for (int i = 0; i < 4; ++i) {
            int g = lr + 4 * i;
            uint4 v = {0u, 0u, 0u, 0u};
            if (row < NN) v = *reinterpret_cast<const uint4*>(hb + (size_t)row * HH + g * 8);
            *reinterpret_cast<uint4*>(&Xs[l][g * 8]) = v;
        }
    }
    for (int i = 0; i < 8; ++i) {
        int idx = t + 256 * i;
        int row = idx >> 4, g = idx & 15;
        *reinterpret_cast<uint4*>(&Ws[row][g * 8]) =
            *reinterpret_cast<const uint4*>(rootT + row * HH + g * 8);
    }
    __syncthreads();

    int w = t >> 6, lane = t & 63;
    int lr16 = lane & 15, kg = lane >> 4;
    v4f acc[8];
    for (int n = 0; n < 8; ++n) acc[n] = (v4f){0.f, 0.f, 0.f, 0.f};
#pragma unroll
    for (int kk = 0; kk < 4; ++kk) {
        int k0 = kk * 32 + kg * 8;
        v8bf a = *reinterpret_cast<const v8bf*>(&Xs[w * 16 + lr16][k0]);
#pragma unroll
        for (int n = 0; n < 8; ++n) {
            v8bf b = *reinterpret_cast<const v8bf*>(&Ws[n * 16 + lr16][k0]);
            acc[n] = __builtin_amdgcn_mfma_f32_16x16x32_bf16(a, b, acc[n], 0, 0, 0);
        }
    }
#pragma unroll
    for (int n = 0; n < 8; ++n)
        for (int j = 0; j < 4; ++j) {
            int row = base + w * 16 + kg * 4 + j;
            int col = n * 16 + lr16;
            if (row < NN) tmp[(size_t)row * HH + col] = acc[n][j] + bias[col];
        }
}

// ---------------- edge GEMM -> xe rows (dst-sorted slots), no atomics ------------
__global__ __launch_bounds__(256) void k_edgegemm_x(const unsigned short* __restrict__ hb,
                                                    const unsigned short* __restrict__ Wt,
                                                    const int* __restrict__ src_s,
                                                    const int* __restrict__ chunk_rel,
                                                    const float* __restrict__ norm_s,
                                                    const int* __restrict__ dpos_s,
                                                    const int* __restrict__ totals,
                                                    unsigned short* __restrict__ xe) {
    int ebase = blockIdx.x * TILE;
    if (ebase >= totals[0]) return;
    __shared__ __align__(16) unsigned short Xs[TILE][HH + 8];
    __shared__ __align__(16) unsigned short Ws[HH][HH + 8];
    __shared__ int   src_l[TILE];
    __shared__ int   dpos_l[TILE];
    __shared__ float nrm_l[TILE];
    int t = threadIdx.x;
    if (t < TILE) {
        src_l[t]  = src_s[ebase + t];
        dpos_l[t] = dpos_s[ebase + t];
        nrm_l[t]  = norm_s[ebase + t];
    }
    int rel = chunk_rel[blockIdx.x];  // single-relation chunk by construction
    __syncthreads();

    {
        int l = t >> 2, lr = t & 3;
        int srow = src_l[l];
        for (int i = 0; i < 4; ++i) {
            int g = lr + 4 * i;
            *reinterpret_cast<uint4*>(&Xs[l][g * 8]) =
                *reinterpret_cast<const uint4*>(hb + (size_t)srow * HH + g * 8);
        }
    }
    const unsigned short* Wr = Wt + (size_t)rel * HH * HH;
    for (int i = 0; i < 8; ++i) {
        int idx = t + 256 * i;
        int row = idx >> 4, g = idx & 15;
        *reinterpret_cast<uint4*>(&Ws[row][g * 8]) =
            *reinterpret_cast<const uint4*>(Wr + row * HH + g * 8);
    }
    __syncthreads();

    int w = t >> 6, lane = t & 63;
    int lr16 = lane & 15, kg = lane >> 4;
    v4f acc[8];
    for (int n = 0; n < 8; ++n) acc[n] = (v4f){0.f, 0.f, 0.f, 0.f};
#pragma unroll
    for (int kk = 0; kk < 4; ++kk) {
        int k0 = kk * 32 + kg * 8;
        v8bf a = *reinterpret_cast<const v8bf*>(&Xs[w * 16 + lr16][k0]);
#pragma unroll
        for (int n = 0; n < 8; ++n) {
            v8bf b = *reinterpret_cast<const v8bf*>(&Ws[n * 16 + lr16][k0]);
            acc[n] = __builtin_amdgcn_mfma_f32_16x16x32_bf16(a, b, acc[n], 0, 0, 0);
        }
    }
    __syncthreads();  // done reading Xs/Ws; reuse Xs as bf16 output staging
#pragma unroll
    for (int n = 0; n < 8; ++n)
        for (int j = 0; j < 4; ++j) {
            int slot = w * 16 + kg * 4 + j;
            Xs[slot][n * 16 + lr16] = f2b(acc[n][j] * nrm_l[slot]);
        }
    __syncthreads();
    {
        int l = t >> 2, lr = t & 3;
        size_t drow = (size_t)dpos_l[l];
        for (int i = 0; i < 4; ++i) {
            int g = lr + 4 * i;
            *reinterpret_cast<uint4*>(xe + drow * HH + g * 8) =
                *reinterpret_cast<uint4*>(&Xs[l][g * 8]);
        }
    }
}

// ---------------- fallback: atomic edge GEMM (if ws too small for xe) ------------
__global__ __launch_bounds__(256) void k_edgegemm_at(const unsigned short* __restrict__ hb,
                                                     const unsigned short* __restrict__ Wt,
                                                     const int* __restrict__ src_s,
                                                     const int* __restrict__ dst_s,
                                                     const int* __restrict__ chunk_rel,
                                                     const float* __restrict__ norm_s,
                                                     const int* __restrict__ totals,
                                                     float* __restrict__ tmp) {
    int ebase = blockIdx.x * TILE;
    if (ebase >= totals[0]) return;
    __shared__ __align__(16) unsigned short Xs[TILE][HH + 8];
    __shared__ __align__(16) unsigned short Ws[HH][HH + 8];
    __shared__ int   src_l[TILE];
    __shared__ int   dst_l[TILE];
    __shared__ float nrm_l[TILE];
    int t = threadIdx.x;
    if (t < TILE) {
        src_l[t] = src_s[ebase + t];
        dst_l[t] = dst_s[ebase + t];
        nrm_l[t] = norm_s[ebase + t];
    }
    int rel = chunk_rel[blockIdx.x];
    __syncthreads();
    {
        int l = t >> 2, lr = t & 3;
        int srow = src_l[l];
        for (int i = 0; i < 4; ++i) {
            int g = lr + 4 * i;
            *reinterpret_cast<uint4*>(&Xs[l][g * 8]) =
                *reinterpret_cast<const uint4*>(hb + (size_t)srow * HH + g * 8);
        }
    }
    const unsigned short* Wr = Wt + (size_t)rel * HH * HH;
    for (int i = 0; i < 8; ++i) {
        int idx = t + 256 * i;
        int row = idx >> 4, g = idx & 15;
        *reinterpret_cast<uint4*>(&Ws[row][g * 8]) =
            *reinterpret_cast<const uint4*>(Wr + row * HH + g * 8);
    }
    __syncthreads();
    int w = t >> 6, lane = t & 63;
    int lr16 = lane & 15, kg = lane >> 4;
    v4f acc[8];
    for (int n = 0; n < 8; ++n) acc[n] = (v4f){0.f, 0.f, 0.f, 0.f};
#pragma unroll
    for (int kk = 0; kk < 4; ++kk) {
        int k0 = kk * 32 + kg * 8;
        v8bf a = *reinterpret_cast<const v8bf*>(&Xs[w * 16 + lr16][k0]);
#pragma unroll
        for (int n = 0; n < 8; ++n) {
            v8bf b = *reinterpret_cast<const v8bf*>(&Ws[n * 16 + lr16][k0]);
            acc[n] = __builtin_amdgcn_mfma_f32_16x16x32_bf16(a, b, acc[n], 0, 0, 0);
        }
    }
#pragma unroll
    for (int n = 0; n < 8; ++n)
        for (int j = 0; j < 4; ++j) {
            int slot = w * 16 + kg * 4 + j;
            int col  = n * 16 + lr16;
            atomicAdd(&tmp[(size_t)dst_l[slot] * HH + col], acc[n][j] * nrm_l[slot]);
        }
}

// ---------------- chunked coalesced segmented reduce over dst-sorted xe ----------
// Privateness of a segment is derived from the ballot mask: a segment that
// starts at an internal boundary ("fresh") and ends at an internal boundary is
// entirely inside this chunk -> non-atomic RMW. Only the first (bit0) and last
// (check ds2[c0+CH]) segments can straddle chunk borders.
__global__ __launch_bounds__(256) void k_aggseg(const unsigned int* __restrict__ xe32,
                                                const int* __restrict__ ds2,
                                                float* __restrict__ tmp) {
    int wid = (blockIdx.x * blockDim.x + threadIdx.x) >> 6;
    int lane = threadIdx.x & 63;
    if (wid >= NE / CH) return;               // NE % CH == 0: all chunks full
    int c0 = wid * CH;

    int dme = ds2[c0 + lane];
    int dpre = __shfl_up(dme, 1);
    if (lane == 0) dpre = (c0 == 0) ? -1 : ds2[c0 - 1];
    unsigned long long bmask = __ballot(dme != dpre);
    int dnext = (c0 + CH < NE) ? ds2[c0 + CH] : -1;

    int dcur = __shfl(dme, 0);
    bool fresh = (bmask & 1ull) != 0;         // first segment starts cleanly here?
    float a0 = 0.f, a1 = 0.f;
    for (int q0 = 0; q0 < CH; q0 += 16) {
        unsigned int v[16];
#pragma unroll
        for (int j = 0; j < 16; ++j)
            v[j] = xe32[(size_t)(c0 + q0 + j) * 64 + lane];
#pragma unroll
        for (int j = 0; j < 16; ++j) {
            int q = q0 + j;
            if (q && ((bmask >> q) & 1ull)) {
                float* base = tmp + (size_t)dcur * HH + lane * 2;
                if (fresh) {
                    float2* b2 = reinterpret_cast<float2*>(base);
                    float2 o = *b2; o.x += a0; o.y += a1; *b2 = o;
                } else {
                    atomicAdd(base, a0);
                    atomicAdd(base + 1, a1);
                }
                a0 = 0.f; a1 = 0.f;
                dcur = __shfl(dme, q);
                fresh = true;                 // started at internal boundary
            }
            a0 += __uint_as_float(v[j] << 16);
            a1 += __uint_as_float(v[j] & 0xffff0000u);
        }
    }
    {
        bool endclean = (dnext != dcur);
        float* base = tmp + (size_t)dcur * HH + lane * 2;
        if (fresh && endclean) {
            float2* b2 = reinterpret_cast<float2*>(base);
            float2 o = *b2; o.x += a0; o.y += a1; *b2 = o;
        } else {
            atomicAdd(base, a0);
            atomicAdd(base + 1, a1);
        }
    }
}

// ---------------- BN stage 1: per-block column partial sums (no atomics) ---------
__global__ __launch_bounds__(256) void k_bnsum1(const float* __restrict__ tmp,
                                                float* __restrict__ psum,
                                                float* __restrict__ psq) {
    int t = threadIdx.x;
    int rg = t >> 5, lane = t & 31;           // 8 row-groups x 32 lanes (float4 cols)
    int base = blockIdx.x * RPB_BN;
    v4f s = {0.f, 0.f, 0.f, 0.f}, q = {0.f, 0.f, 0.f, 0.f};
#pragma unroll 4
    for (int i = 0; i < RPB_BN / 8; ++i) {
        int row = base + rg + 8 * i;
        if (row < NN) {
            v4f v = *reinterpret_cast<const v4f*>(tmp + (size_t)row * HH + lane * 4);
            s += v; q += v * v;
        }
    }
    __shared__ v4f shs[8][32], shq[8][32];
    shs[rg][lane] = s; shq[rg][lane] = q;
    __syncthreads();
    if (rg == 0) {
        v4f ts = shs[0][lane], tq = shq[0][lane];
#pragma unroll
        for (int k = 1; k < 8; ++k) { ts += shs[k][lane]; tq += shq[k][lane]; }
        int b = blockIdx.x;
#pragma unroll
        for (int j = 0; j < 4; ++j) {
            psum[(size_t)(lane * 4 + j) * NBLK_BN + b] = ts[j];
            psq [(size_t)(lane * 4 + j) * NBLK_BN + b] = tq[j];
        }
    }
}

// ---------------- BN stage 2: reduce partials, emit affine coefficients ----------
__global__ void k_bnsum2(const float* __restrict__ psum, const float* __restrict__ psq,
                         const float* __restrict__ g, const float* __restrict__ be,
                         float* __restrict__ sc_g, float* __restrict__ shf_g) {
    __shared__ float ssum[HH], ssq[HH];
    int t = threadIdx.x;
    int col = t & 127;
    const float* row = ((t < 128) ? psum : psq) + (size_t)col * NBLK_BN;
    v4f a = {0.f, 0.f, 0.f, 0.f};
    for (int i = 0; i < NBLK_BN / 4; ++i)
        a += *reinterpret_cast<const v4f*>(row + i * 4);
    float acc = a[0] + a[1] + a[2] + a[3];
    if (t < 128) ssum[col] = acc; else ssq[col] = acc;
    __syncthreads();
    if (t < 128) {
        float inv_n = 1.0f / (float)NN;
        float mean = ssum[col] * inv_n;
        float var = ssq[col] * inv_n - mean * mean;
        float sc = g[col] * rsqrtf(var + BN_EPS);
        sc_g[col] = sc;
        shf_g[col] = be[col] - mean * sc;
    }
}

// ---------------- BN apply + ReLU (vectorized float4) ----------------
__global__ void k_bnapply(const float* __restrict__ tmp, const float* __restrict__ sc_g,
                          const float* __restrict__ shf_g,
                          unsigned short* __restrict__ hout,
                          float* __restrict__ fout, int write_bf16) {
    int idx = blockIdx.x * blockDim.x + threadIdx.x;   // float4 index
    if (idx >= NN * HH / 4) return;
    int c4 = (idx & 31) * 4;                            // HH/4 = 32 quads per row
    v4f v  = *reinterpret_cast<const v4f*>(tmp + (size_t)idx * 4);
    v4f sc = *reinterpret_cast<const v4f*>(sc_g + c4);
    v4f sh = *reinterpret_cast<const v4f*>(shf_g + c4);
    v4f r;
#pragma unroll
    for (int j = 0; j < 4; ++j) r[j] = fmaxf(v[j] * sc[j] + sh[j], 0.f);
    if (write_bf16) {
        uint2 u;
        u.x = (unsigned int)f2b(r[0]) | ((unsigned int)f2b(r[1]) << 16);
        u.y = (unsigned int)f2b(r[2]) | ((unsigned int)f2b(r[3]) << 16);
        *reinterpret_cast<uint2*>(hout + (size_t)idx * 4) = u;
    } else {
        *reinterpret_cast<v4f*>(fout + (size_t)idx * 4) = r;
    }
}

// ---------------- workspace layout (xe LAST so fallback fits small ws) -----------
constexpr size_t OFF_DEG  = 0;                                    // N*R*4
constexpr size_t OFF_HB   = OFF_DEG + (size_t)NN * RR * 4;
constexpr size_t OFF_TMP  = OFF_HB + (size_t)NN * HH * 2;
constexpr size_t OFF_W1T  = OFF_TMP + (size_t)NN * HH * 4;
constexpr size_t OFF_W2T  = OFF_W1T + (size_t)RR * HH * HH * 2;
constexpr size_t OFF_R1T  = OFF_W2T + (size_t)RR * HH * HH * 2;
constexpr size_t OFF_R2T  = OFF_R1T + (size_t)HH * HH * 2;
constexpr size_t OFF_SRCS = OFF_R2T + (size_t)HH * HH * 2;
constexpr size_t OFF_DSTS = OFF_SRCS + (size_t)EPAD * 4;
constexpr size_t OFF_NRMS = OFF_DSTS + (size_t)EPAD * 4;
constexpr size_t OFF_DPOS = OFF_NRMS + (size_t)EPAD * 4;
constexpr size_t OFF_DS2  = OFF_DPOS + (size_t)EPAD * 4;          // dst per sorted slot
constexpr size_t OFF_CREL = OFF_DS2 + (size_t)EPAD * 4;           // chunk -> relation
constexpr size_t OFF_CNTD = OFF_CREL + ((size_t)NCHMAX * 4 + 255 & ~(size_t)255);
constexpr size_t OFF_OFFD = OFF_CNTD + ((size_t)(NN + 1) * 4 + 255 & ~(size_t)255);
constexpr size_t OFF_CURD = OFF_OFFD + ((size_t)(NN + 1) * 4 + 255 & ~(size_t)255);
constexpr size_t OFF_BSUM = OFF_CURD + ((size_t)NN * 4 + 255 & ~(size_t)255);
constexpr size_t OFF_CTRL = OFF_BSUM + ((size_t)NB_PS * 4 + 255 & ~(size_t)255);
constexpr size_t OFF_SC   = OFF_CTRL + 512;                       // 128 floats
constexpr size_t OFF_SHF  = OFF_SC + 512;
constexpr size_t OFF_PSUM = OFF_SHF + 512;                        // 128*NBLK_BN floats
constexpr size_t OFF_PSQ  = OFF_PSUM + (size_t)HH * NBLK_BN * 4;
constexpr size_t OFF_XE   = (OFF_PSQ + (size_t)HH * NBLK_BN * 4 + 255) & ~(size_t)255;
constexpr size_t WS_MIN   = OFF_XE;                               // ~108 MB (fallback)
constexpr size_t WS_FULL  = OFF_XE + (size_t)EPAD * HH * 2;       // ~261 MB

extern "C" void kernel_launch(void* const* d_in, const int* in_sizes, int n_in,
                              void* d_out, int out_size, void* d_ws, size_t ws_size,
                              hipStream_t stream) {
    const int*   x     = (const int*)d_in[0];
    const int*   eidx  = (const int*)d_in[1];   // (2,E) row-major: src then dst
    const int*   et    = (const int*)d_in[2];
    const float* emb   = (const float*)d_in[3];
    const float* W1    = (const float*)d_in[4];
    const float* root1 = (const float*)d_in[5];
    const float* b1    = (const float*)d_in[6];
    const float* g1    = (const float*)d_in[7];
    const float* be1   = (const float*)d_in[8];
    const float* W2    = (const float*)d_in[9];
    const float* root2 = (const float*)d_in[10];
    const float* b2    = (const float*)d_in[11];
    const float* g2    = (const float*)d_in[12];
    const float* be2   = (const float*)d_in[13];
    float* out = (float*)d_out;

    if (ws_size < WS_MIN) return;  // diagnosable: out stays poisoned
    const bool full = (ws_size >= WS_FULL);
    const int need_dst = full ? 0 : 1;

    char* ws = (char*)d_ws;
    int*   deg    = (int*)(ws + OFF_DEG);
    unsigned short* hb = (unsigned short*)(ws + OFF_HB);
    float* tmp    = (float*)(ws + OFF_TMP);
    unsigned short* W1t = (unsigned short*)(ws + OFF_W1T);
    unsigned short* W2t = (unsigned short*)(ws + OFF_W2T);
    unsigned short* r1t = (unsigned short*)(ws + OFF_R1T);
    unsigned short* r2t = (unsigned short*)(ws + OFF_R2T);
    int*   src_s  = (int*)(ws + OFF_SRCS);
    int*   dst_s  = (int*)(ws + OFF_DSTS);
    float* norm_s = (float*)(ws + OFF_NRMS);
    int*   dpos_s = (int*)(ws + OFF_DPOS);
    int*   ds2    = (int*)(ws + OFF_DS2);
    int*   crel   = (int*)(ws + OFF_CREL);
    int*   cnt_d  = (int*)(ws + OFF_CNTD);
    int*   off_d  = (int*)(ws + OFF_OFFD);
    int*   cur_d  = (int*)(ws + OFF_CURD);
    int*   bsum   = (int*)(ws + OFF_BSUM);
    int*   cnt    = (int*)(ws + OFF_CTRL);
    int*   cursor = cnt + 32;
    int*   totals = cnt + 64;
    float* sc_g   = (float*)(ws + OFF_SC);
    float* shf_g  = (float*)(ws + OFF_SHF);
    float* psum   = (float*)(ws + OFF_PSUM);
    float* psq    = (float*)(ws + OFF_PSQ);
    unsigned short* xe = (unsigned short*)(ws + OFF_XE);

    const int* srcp = eidx;
    const int* dstp = eidx + NE;

    hipMemsetAsync(deg, 0, (size_t)NN * RR * 4, stream);
    hipMemsetAsync(cnt, 0, 512, stream);

    k_hist<<<(NE + 255) / 256, 256, 0, stream>>>(dstp, et, deg, cnt);
    k_degsum<<<(NN + 255) / 256, 256, 0, stream>>>(deg, cnt_d);
    k_scan<<<1, 256, 0, stream>>>(cnt, cursor, totals, src_s, dst_s, norm_s,
                                  dpos_s, crel, need_dst);
    k_psum1<<<NB_PS, 256, 0, stream>>>(cnt_d, bsum);
    k_psum2<<<1, 512, 0, stream>>>(bsum);
    k_psum3<<<NB_PS, 256, 0, stream>>>(cnt_d, bsum, off_d, cur_d);
    k_fillds2<<<(NN + 255) / 256, 256, 0, stream>>>(off_d, ds2);
    k_scatter<<<(NE + 255) / 256, 256, 0, stream>>>(srcp, dstp, et, deg, cursor, cur_d,
                                                    src_s, dst_s, norm_s, dpos_s,
                                                    need_dst);
    k_convW<<<(RR * HH * HH + 255) / 256, 256, 0, stream>>>(W1, W1t, RR * HH * HH);
    k_convW<<<(RR * HH * HH + 255) / 256, 256, 0, stream>>>(W2, W2t, RR * HH * HH);
    k_convW<<<(HH * HH + 255) / 256, 256, 0, stream>>>(root1, r1t, HH * HH);
    k_convW<<<(HH * HH + 255) / 256, 256, 0, stream>>>(root2, r2t, HH * HH);
    k_embed<<<(NN * HH + 255) / 256, 256, 0, stream>>>(x, emb, hb);

    const unsigned short* Wts[2] = {W1t, W2t};
    const unsigned short* rts[2] = {r1t, r2t};
    const float* biases[2] = {b1, b2};
    const float* gs[2]     = {g1, g2};
    const float* bes[2]    = {be1, be2};

    const int nchunks = NE / CH;                 // 9375
    for (int layer = 0; layer < 2; ++layer) {
        k_rootgemm<<<(NN + TILE - 1) / TILE, 256, 0, stream>>>(hb, rts[layer],
                                                               biases[layer], tmp);
        if (full) {
            k_edgegemm_x<<<EPAD / TILE, 256, 0, stream>>>(hb, Wts[layer], src_s, crel,
                                                          norm_s, dpos_s, totals, xe);
            k_aggseg<<<(nchunks + 3) / 4, 256, 0, stream>>>((const unsigned int*)xe,
                                                            ds2, tmp);
        } else {
            k_edgegemm_at<<<EPAD / TILE, 256, 0, stream>>>(hb, Wts[layer], src_s, dst_s,
                                                           crel, norm_s, totals, tmp);
        }
        k_bnsum1<<<NBLK_BN, 256, 0, stream>>>(tmp, psum, psq);
        k_bnsum2<<<1, 256, 0, stream>>>(psum, psq, gs[layer], bes[layer], sc_g, shf_g);
        k_bnapply<<<(NN * HH / 4 + 255) / 256, 256, 0, stream>>>(tmp, sc_g, shf_g,
                                                                 hb, out, layer == 0);
    }
}